// Round 1
// baseline (1379.539 us; speedup 1.0000x reference)
//
#include <hip/hip_runtime.h>
#include <math.h>

#define HDIM 256
#define NPT0 16384
#define NPTF 32768
#define NB_F 1024   // field: 1024 blocks x 4 waves x 2 pts x 4 iters = 32768
#define NB_B 1024   // bc:    1024 blocks x 4 waves x 4 pts           = 16384

struct alignas(16) f4 { float v[4]; };

__device__ __forceinline__ f4 ldg4(const float* p) {
  return *reinterpret_cast<const f4*>(p);
}

__device__ __forceinline__ void fmaacc(f4& a, float s, const f4& w) {
#pragma unroll
  for (int u = 0; u < 4; ++u) a.v[u] = fmaf(s, w.v[u], a.v[u]);
}

// ---------------------------------------------------------------------------
// Field kernel: per wave, 2 points at a time. LDS layout per wave:
// hS[p*HDIM + i] = f4 {h, dh_x, dh_y, dh_z} for neuron i of point p.
// ---------------------------------------------------------------------------
__global__ __launch_bounds__(256) void field_kernel(
    const float* __restrict__ xyz_f,
    const float* __restrict__ lb, const float* __restrict__ ub,
    const float* __restrict__ W0, const float* __restrict__ b0,
    const float* __restrict__ W1, const float* __restrict__ b1,
    const float* __restrict__ W2, const float* __restrict__ b2,
    const float* __restrict__ W3, const float* __restrict__ b3,
    const float* __restrict__ W4, const float* __restrict__ b4,
    const float* __restrict__ W5, const float* __restrict__ b5,
    const float* __restrict__ W6, const float* __restrict__ b6,
    float* __restrict__ part_div2, float* __restrict__ part_jxb)
{
  __shared__ f4 ldsF[4 * 2 * HDIM];  // 32 KB
  const int lane = threadIdx.x & 63;
  const int wv   = threadIdx.x >> 6;
  const int gw   = blockIdx.x * 4 + wv;   // 0..4095
  f4* hS = &ldsF[wv * 2 * HDIM];

  const float lbx = lb[0], lby = lb[1], lbz = lb[2];
  const float sx = 2.f / (ub[0] - lbx);
  const float sy = 2.f / (ub[1] - lby);
  const float sz = 2.f / (ub[2] - lbz);

  const float* Wm[5] = {W1, W2, W3, W4, W5};
  const float* bm[5] = {b1, b2, b3, b4, b5};

  // layer-0 weights (3 rows) + bias, hoisted
  const f4 w0r0 = ldg4(W0 + 0 * HDIM + 4 * lane);
  const f4 w0r1 = ldg4(W0 + 1 * HDIM + 4 * lane);
  const f4 w0r2 = ldg4(W0 + 2 * HDIM + 4 * lane);
  const f4 bv0  = ldg4(b0 + 4 * lane);

  float acc_div2 = 0.f, acc_jxb = 0.f;

  for (int it = 0; it < 4; ++it) {
    const int pt0 = it * 8192 + gw * 2;

    // ---- layer 0 (3 -> 256, tanh) ----
    __syncthreads();
#pragma unroll
    for (int p = 0; p < 2; ++p) {
      const int pt = pt0 + p;
      const float hx = (xyz_f[pt * 3 + 0] - lbx) * sx - 1.f;
      const float hy = (xyz_f[pt * 3 + 1] - lby) * sy - 1.f;
      const float hz = (xyz_f[pt * 3 + 2] - lbz) * sz - 1.f;
#pragma unroll
      for (int u = 0; u < 4; ++u) {
        const float zz = bv0.v[u] + hx * w0r0.v[u] + hy * w0r1.v[u] + hz * w0r2.v[u];
        const float th = tanhf(zz);
        const float g  = 1.f - th * th;
        f4 e;
        e.v[0] = th;
        e.v[1] = g * sx * w0r0.v[u];
        e.v[2] = g * sy * w0r1.v[u];
        e.v[3] = g * sz * w0r2.v[u];
        hS[p * HDIM + 4 * lane + u] = e;
      }
    }
    __syncthreads();

    // ---- layers 1..5 (256 -> 256, tanh) ----
    for (int l = 0; l < 5; ++l) {
      const float* Wl = Wm[l];
      const f4 bv = ldg4(bm[l] + 4 * lane);
      f4 acc[2][4];
#pragma unroll
      for (int p = 0; p < 2; ++p)
#pragma unroll
        for (int s = 0; s < 4; ++s)
#pragma unroll
          for (int u = 0; u < 4; ++u) acc[p][s].v[u] = 0.f;

#pragma unroll 2
      for (int i = 0; i < HDIM; ++i) {
        const f4 w   = ldg4(Wl + i * HDIM + 4 * lane);
        const f4 h0v = hS[i];
        const f4 h1v = hS[HDIM + i];
        fmaacc(acc[0][0], h0v.v[0], w);
        fmaacc(acc[0][1], h0v.v[1], w);
        fmaacc(acc[0][2], h0v.v[2], w);
        fmaacc(acc[0][3], h0v.v[3], w);
        fmaacc(acc[1][0], h1v.v[0], w);
        fmaacc(acc[1][1], h1v.v[1], w);
        fmaacc(acc[1][2], h1v.v[2], w);
        fmaacc(acc[1][3], h1v.v[3], w);
      }
      __syncthreads();
#pragma unroll
      for (int p = 0; p < 2; ++p)
#pragma unroll
        for (int u = 0; u < 4; ++u) {
          const float zz = acc[p][0].v[u] + bv.v[u];
          const float th = tanhf(zz);
          const float g  = 1.f - th * th;
          f4 e;
          e.v[0] = th;
          e.v[1] = g * acc[p][1].v[u];
          e.v[2] = g * acc[p][2].v[u];
          e.v[3] = g * acc[p][3].v[u];
          hS[p * HDIM + 4 * lane + u] = e;
        }
      __syncthreads();
    }

    // ---- layer 6 (256 -> 3, linear) + physics ----
#pragma unroll
    for (int p = 0; p < 2; ++p) {
      float r[15];
#pragma unroll
      for (int t = 0; t < 15; ++t) r[t] = 0.f;
#pragma unroll
      for (int ii = 0; ii < 4; ++ii) {
        const int i = 4 * lane + ii;
        const f4 hv = hS[p * HDIM + i];
#pragma unroll
        for (int o = 0; o < 3; ++o) {
          const float w = W6[i * 3 + o];
          r[o]          = fmaf(hv.v[0], w, r[o]);
          r[3 + 0 + o]  = fmaf(hv.v[1], w, r[3 + 0 + o]);
          r[3 + 3 + o]  = fmaf(hv.v[2], w, r[3 + 3 + o]);
          r[3 + 6 + o]  = fmaf(hv.v[3], w, r[3 + 6 + o]);
        }
      }
#pragma unroll
      for (int t = 0; t < 15; ++t) {
        float v = r[t];
        for (int off = 32; off > 0; off >>= 1) v += __shfl_down(v, off);
        r[t] = v;
      }
      if (lane == 0) {
        const float bx = r[0] + b6[0];
        const float by = r[1] + b6[1];
        const float bz = r[2] + b6[2];
        const float j00 = r[3],  j01 = r[4],  j02 = r[5];
        const float j10 = r[6],  j11 = r[7],  j12 = r[8];
        const float j20 = r[9],  j21 = r[10], j22 = r[11];
        const float div = j00 + j11 + j22;
        const float jx = j12 - j21;
        const float jy = j20 - j02;
        const float jz = j01 - j10;
        const float e1 = jy * bz - jz * by;
        const float e2 = jz * bx - jx * bz;
        const float e3 = jx * by - jy * bx;
        acc_div2 += div * div;
        acc_jxb  += e1 * e1 + e2 * e2 + e3 * e3;
      }
    }
  }

  if (lane == 0) {
    part_div2[gw] = acc_div2;
    part_jxb[gw]  = acc_jxb;
  }
}

// ---------------------------------------------------------------------------
// BC kernel: per wave, 4 points (primal only). LDS per wave:
// hS[i].v[p] = activation of neuron i for point p.
// ---------------------------------------------------------------------------
__global__ __launch_bounds__(256) void bc_kernel(
    const float* __restrict__ x0, const float* __restrict__ y0,
    const float* __restrict__ bx0, const float* __restrict__ by0,
    const float* __restrict__ bz0,
    const float* __restrict__ lb, const float* __restrict__ ub,
    const float* __restrict__ W0, const float* __restrict__ b0,
    const float* __restrict__ W1, const float* __restrict__ b1,
    const float* __restrict__ W2, const float* __restrict__ b2,
    const float* __restrict__ W3, const float* __restrict__ b3,
    const float* __restrict__ W4, const float* __restrict__ b4,
    const float* __restrict__ W5, const float* __restrict__ b5,
    const float* __restrict__ W6, const float* __restrict__ b6,
    float* __restrict__ part_bc)
{
  __shared__ f4 ldsB[4 * HDIM];  // 16 KB
  const int lane = threadIdx.x & 63;
  const int wv   = threadIdx.x >> 6;
  const int gw   = blockIdx.x * 4 + wv;   // 0..4095
  f4* hS = &ldsB[wv * HDIM];

  const float lbx = lb[0], lby = lb[1], lbz = lb[2];
  const float sx = 2.f / (ub[0] - lbx);
  const float sy = 2.f / (ub[1] - lby);
  const float sz = 2.f / (ub[2] - lbz);

  const float* Wm[5] = {W1, W2, W3, W4, W5};
  const float* bm[5] = {b1, b2, b3, b4, b5};

  const f4 w0r0 = ldg4(W0 + 0 * HDIM + 4 * lane);
  const f4 w0r1 = ldg4(W0 + 1 * HDIM + 4 * lane);
  const f4 w0r2 = ldg4(W0 + 2 * HDIM + 4 * lane);
  const f4 bv0  = ldg4(b0 + 4 * lane);

  // ---- layer 0 ----
  const float hzc = (0.f - lbz) * sz - 1.f;
  float th0[4][4];  // [p][u]
#pragma unroll
  for (int p = 0; p < 4; ++p) {
    const int pt = gw * 4 + p;
    const float hx = (x0[pt] - lbx) * sx - 1.f;
    const float hy = (y0[pt] - lby) * sy - 1.f;
#pragma unroll
    for (int u = 0; u < 4; ++u) {
      const float zz = bv0.v[u] + hx * w0r0.v[u] + hy * w0r1.v[u] + hzc * w0r2.v[u];
      th0[p][u] = tanhf(zz);
    }
  }
  __syncthreads();
#pragma unroll
  for (int u = 0; u < 4; ++u) {
    f4 e;
#pragma unroll
    for (int p = 0; p < 4; ++p) e.v[p] = th0[p][u];
    hS[4 * lane + u] = e;
  }
  __syncthreads();

  // ---- layers 1..5 ----
  for (int l = 0; l < 5; ++l) {
    const float* Wl = Wm[l];
    const f4 bv = ldg4(bm[l] + 4 * lane);
    f4 acc[4];  // acc[p].v[u]
#pragma unroll
    for (int p = 0; p < 4; ++p)
#pragma unroll
      for (int u = 0; u < 4; ++u) acc[p].v[u] = 0.f;

#pragma unroll 2
    for (int i = 0; i < HDIM; ++i) {
      const f4 w  = ldg4(Wl + i * HDIM + 4 * lane);
      const f4 hv = hS[i];
      fmaacc(acc[0], hv.v[0], w);
      fmaacc(acc[1], hv.v[1], w);
      fmaacc(acc[2], hv.v[2], w);
      fmaacc(acc[3], hv.v[3], w);
    }
    __syncthreads();
#pragma unroll
    for (int u = 0; u < 4; ++u) {
      f4 e;
#pragma unroll
      for (int p = 0; p < 4; ++p) e.v[p] = tanhf(acc[p].v[u] + bv.v[u]);
      hS[4 * lane + u] = e;
    }
    __syncthreads();
  }

  // ---- layer 6 + BC loss ----
  float r[12];  // r[p*3+o]
#pragma unroll
  for (int t = 0; t < 12; ++t) r[t] = 0.f;
#pragma unroll
  for (int ii = 0; ii < 4; ++ii) {
    const int i = 4 * lane + ii;
    const f4 hv = hS[i];
#pragma unroll
    for (int o = 0; o < 3; ++o) {
      const float w = W6[i * 3 + o];
#pragma unroll
      for (int p = 0; p < 4; ++p) r[p * 3 + o] = fmaf(hv.v[p], w, r[p * 3 + o]);
    }
  }
#pragma unroll
  for (int t = 0; t < 12; ++t) {
    float v = r[t];
    for (int off = 32; off > 0; off >>= 1) v += __shfl_down(v, off);
    r[t] = v;
  }
  if (lane == 0) {
    float accb = 0.f;
#pragma unroll
    for (int p = 0; p < 4; ++p) {
      const int pt = gw * 4 + p;
      const float ex = r[p * 3 + 0] + b6[0] - bx0[pt];
      const float ey = r[p * 3 + 1] + b6[1] - by0[pt];
      const float ez = r[p * 3 + 2] + b6[2] - bz0[pt];
      accb += ex * ex + ey * ey + ez * ez;
    }
    part_bc[gw] = accb;
  }
}

// ---------------------------------------------------------------------------
// Final reduction: ws[0,4096)=div2, [4096,8192)=jxb, [8192,12288)=bc
// ---------------------------------------------------------------------------
__global__ void reduce_kernel(const float* __restrict__ ws, float* __restrict__ out)
{
  __shared__ float sdata[12];
  const int tid = threadIdx.x;
  const int lane = tid & 63, wv = tid >> 6;
  float sd = 0.f, sj = 0.f, sb = 0.f;
  for (int i = tid; i < 4096; i += 256) {
    sd += ws[i];
    sj += ws[4096 + i];
    sb += ws[8192 + i];
  }
  for (int off = 32; off > 0; off >>= 1) {
    sd += __shfl_down(sd, off);
    sj += __shfl_down(sj, off);
    sb += __shfl_down(sb, off);
  }
  if (lane == 0) {
    sdata[wv * 3 + 0] = sd;
    sdata[wv * 3 + 1] = sj;
    sdata[wv * 3 + 2] = sb;
  }
  __syncthreads();
  if (tid == 0) {
    float d = 0.f, j = 0.f, b = 0.f;
    for (int w = 0; w < 4; ++w) {
      d += sdata[w * 3 + 0];
      j += sdata[w * 3 + 1];
      b += sdata[w * 3 + 2];
    }
    out[0] = b / (float)NPT0 + d / (float)NPTF + j / (float)NPTF;
  }
}

extern "C" void kernel_launch(void* const* d_in, const int* in_sizes, int n_in,
                              void* d_out, int out_size, void* d_ws, size_t ws_size,
                              hipStream_t stream)
{
  const float* x0    = (const float*)d_in[0];
  const float* y0    = (const float*)d_in[1];
  const float* bx0   = (const float*)d_in[2];
  const float* by0   = (const float*)d_in[3];
  const float* bz0   = (const float*)d_in[4];
  const float* xyz_f = (const float*)d_in[5];
  const float* lb    = (const float*)d_in[6];
  const float* ub    = (const float*)d_in[7];
  const float* W0 = (const float*)d_in[8];
  const float* b0 = (const float*)d_in[9];
  const float* W1 = (const float*)d_in[10];
  const float* b1 = (const float*)d_in[11];
  const float* W2 = (const float*)d_in[12];
  const float* b2 = (const float*)d_in[13];
  const float* W3 = (const float*)d_in[14];
  const float* b3 = (const float*)d_in[15];
  const float* W4 = (const float*)d_in[16];
  const float* b4 = (const float*)d_in[17];
  const float* W5 = (const float*)d_in[18];
  const float* b5 = (const float*)d_in[19];
  const float* W6 = (const float*)d_in[20];
  const float* b6 = (const float*)d_in[21];

  float* ws = (float*)d_ws;

  field_kernel<<<NB_F, 256, 0, stream>>>(xyz_f, lb, ub,
      W0, b0, W1, b1, W2, b2, W3, b3, W4, b4, W5, b5, W6, b6,
      ws, ws + 4096);
  bc_kernel<<<NB_B, 256, 0, stream>>>(x0, y0, bx0, by0, bz0, lb, ub,
      W0, b0, W1, b1, W2, b2, W3, b3, W4, b4, W5, b5, W6, b6,
      ws + 8192);
  reduce_kernel<<<1, 256, 0, stream>>>(ws, (float*)d_out);
}

// Round 2
// 371.979 us; speedup vs baseline: 3.7086x; 3.7086x over previous
//
#include <hip/hip_runtime.h>
#include <math.h>

typedef short bf16x8 __attribute__((ext_vector_type(8)));
typedef short bf16x4 __attribute__((ext_vector_type(4)));
typedef float f32x4 __attribute__((ext_vector_type(4)));

#define NPT0 16384
#define NPTF 32768

__device__ __forceinline__ short f2b(float f) {
  union { float f; unsigned u; } v; v.f = f;
  return (short)((v.u + 0x7FFFu + ((v.u >> 16) & 1u)) >> 16);
}
__device__ __forceinline__ float b2f(short s) {
  union { unsigned u; float f; } v;
  v.u = ((unsigned)(unsigned short)s) << 16;
  return v.f;
}
// swizzled short-index into one [32][256] bf16 plane: fixes 16-way bank
// conflicts on ds_read_b128 A-fragment loads (rows are 512B apart).
__device__ __forceinline__ int swzp(int p, int k) {
  int byte = (p * 256 + k) * 2;
  byte ^= (p & 7) << 4;
  return byte >> 1;
}

// ---------------------------------------------------------------------------
// prep: W1..W5 fp32 [k][n] -> Wt bf16 [layer][n][k]  (B-operand layout)
// ---------------------------------------------------------------------------
__global__ void prep_kernel(const float* __restrict__ W1, const float* __restrict__ W2,
                            const float* __restrict__ W3, const float* __restrict__ W4,
                            const float* __restrict__ W5, short* __restrict__ Wt)
{
  const int layer = blockIdx.x >> 8;              // 256 blocks per layer
  const float* src = layer == 0 ? W1 : layer == 1 ? W2 : layer == 2 ? W3
                   : layer == 3 ? W4 : W5;
  const int i = (blockIdx.x & 255) * 256 + threadIdx.x;  // 0..65535
  const int n = i >> 8, k = i & 255;
  Wt[layer * 65536 + i] = f2b(src[k * 256 + n]);
}

// ---------------------------------------------------------------------------
// field: 32 pts/block, 8 waves. States: 0=h, 1=dx, 2=dy, 3=dz.
// Wave (wv): points [(wv>>2)*16, +16), cols [(wv&3)*64, +64) (4 n-tiles).
// ---------------------------------------------------------------------------
__global__ __launch_bounds__(512, 4) void field_kernel(
    const float* __restrict__ xyz_f,
    const float* __restrict__ lb, const float* __restrict__ ub,
    const float* __restrict__ W0, const float* __restrict__ b0,
    const float* __restrict__ b1, const float* __restrict__ b2,
    const float* __restrict__ b3, const float* __restrict__ b4,
    const float* __restrict__ b5,
    const short* __restrict__ Wt,
    const float* __restrict__ W6, const float* __restrict__ b6,
    float* __restrict__ part_div2, float* __restrict__ part_jxb)
{
  __shared__ short act[4 * 32 * 256];  // 64 KB
  __shared__ float red[16];
  const int tid = threadIdx.x;
  const int lane = tid & 63;
  const int wv = tid >> 6;
  const int c = lane & 15;
  const int kg = lane >> 4;
  const int pbase = (wv >> 2) * 16;
  const int nbase = (wv & 3) * 64;

  const float lbx = lb[0], lby = lb[1], lbz = lb[2];
  const float sx = 2.f / (ub[0] - lbx);
  const float sy = 2.f / (ub[1] - lby);
  const float sz = 2.f / (ub[2] - lbz);

  // ---- layer 0 (3 -> 256): thread t handles point t>>4, 16 neurons ----
  {
    const int p = tid >> 4;
    const int pt = blockIdx.x * 32 + p;
    const int n0 = (tid & 15) * 16;
    const float hx = (xyz_f[pt * 3 + 0] - lbx) * sx - 1.f;
    const float hy = (xyz_f[pt * 3 + 1] - lby) * sy - 1.f;
    const float hz = (xyz_f[pt * 3 + 2] - lbz) * sz - 1.f;
    bf16x8 buf[4][2];
#pragma unroll
    for (int j = 0; j < 16; ++j) {
      const int n = n0 + j;
      const float w0 = W0[n], w1 = W0[256 + n], w2 = W0[512 + n];
      const float z = b0[n] + hx * w0 + hy * w1 + hz * w2;
      const float th = tanhf(z);
      const float g = 1.f - th * th;
      buf[0][j >> 3][j & 7] = f2b(th);
      buf[1][j >> 3][j & 7] = f2b(g * sx * w0);
      buf[2][j >> 3][j & 7] = f2b(g * sy * w1);
      buf[3][j >> 3][j & 7] = f2b(g * sz * w2);
    }
#pragma unroll
    for (int s = 0; s < 4; ++s) {
      *(bf16x8*)&act[s * 8192 + swzp(p, n0)]     = buf[s][0];
      *(bf16x8*)&act[s * 8192 + swzp(p, n0 + 8)] = buf[s][1];
    }
  }
  __syncthreads();

  const int prow = pbase + c;
  const float* const bsArr[5] = {b1, b2, b3, b4, b5};

#pragma unroll
  for (int layer = 0; layer < 5; ++layer) {
    const short* Wl = Wt + layer * 65536;
    const float* bl = bsArr[layer];
    const short* wrow[4];
#pragma unroll
    for (int t = 0; t < 4; ++t) wrow[t] = Wl + (nbase + t * 16 + c) * 256;

    f32x4 acc[4][4];
#pragma unroll
    for (int s = 0; s < 4; ++s)
#pragma unroll
      for (int t = 0; t < 4; ++t) acc[s][t] = (f32x4){0.f, 0.f, 0.f, 0.f};

#pragma unroll
    for (int ks = 0; ks < 8; ++ks) {
      const int k0 = ks * 32 + kg * 8;
      const bf16x8 a0 = *(const bf16x8*)&act[0 * 8192 + swzp(prow, k0)];
      const bf16x8 a1 = *(const bf16x8*)&act[1 * 8192 + swzp(prow, k0)];
      const bf16x8 a2 = *(const bf16x8*)&act[2 * 8192 + swzp(prow, k0)];
      const bf16x8 a3 = *(const bf16x8*)&act[3 * 8192 + swzp(prow, k0)];
#pragma unroll
      for (int t = 0; t < 4; ++t) {
        const bf16x8 bb = *(const bf16x8*)(wrow[t] + k0);
        acc[0][t] = __builtin_amdgcn_mfma_f32_16x16x32_bf16(a0, bb, acc[0][t], 0, 0, 0);
        acc[1][t] = __builtin_amdgcn_mfma_f32_16x16x32_bf16(a1, bb, acc[1][t], 0, 0, 0);
        acc[2][t] = __builtin_amdgcn_mfma_f32_16x16x32_bf16(a2, bb, acc[2][t], 0, 0, 0);
        acc[3][t] = __builtin_amdgcn_mfma_f32_16x16x32_bf16(a3, bb, acc[3][t], 0, 0, 0);
      }
    }
    __syncthreads();  // all GEMM reads of act done

    // epilogue: D lane holds (p=(lane>>4)*4+r, n=nbase+t*16+c)
#pragma unroll
    for (int t = 0; t < 4; ++t) {
      const int n = nbase + t * 16 + c;
      const float bias = bl[n];
#pragma unroll
      for (int r = 0; r < 4; ++r) {
        const int p = pbase + kg * 4 + r;
        const float z = acc[0][t][r] + bias;
        const float th = tanhf(z);
        const float g = 1.f - th * th;
        act[0 * 8192 + swzp(p, n)] = f2b(th);
        act[1 * 8192 + swzp(p, n)] = f2b(g * acc[1][t][r]);
        act[2 * 8192 + swzp(p, n)] = f2b(g * acc[2][t][r]);
        act[3 * 8192 + swzp(p, n)] = f2b(g * acc[3][t][r]);
      }
    }
    __syncthreads();
  }

  // ---- layer 6 (256 -> 3) + physics: wave wv handles pts wv*4 .. wv*4+3 ----
  float ad2 = 0.f, ajx = 0.f;
#pragma unroll
  for (int i = 0; i < 4; ++i) {
    const int p = wv * 4 + i;
    const int k0 = lane * 4;
    float r[4][3] = {};
#pragma unroll
    for (int s = 0; s < 4; ++s) {
      const bf16x4 hv = *(const bf16x4*)&act[s * 8192 + swzp(p, k0)];
#pragma unroll
      for (int e = 0; e < 4; ++e) {
        const float h = b2f(hv[e]);
        const float* w6r = W6 + (k0 + e) * 3;
        r[s][0] = fmaf(h, w6r[0], r[s][0]);
        r[s][1] = fmaf(h, w6r[1], r[s][1]);
        r[s][2] = fmaf(h, w6r[2], r[s][2]);
      }
    }
#pragma unroll
    for (int s = 0; s < 4; ++s)
#pragma unroll
      for (int o = 0; o < 3; ++o) {
        float v = r[s][o];
        for (int off = 32; off > 0; off >>= 1) v += __shfl_down(v, off);
        r[s][o] = v;
      }
    if (lane == 0) {
      const float bx = r[0][0] + b6[0];
      const float by = r[0][1] + b6[1];
      const float bz = r[0][2] + b6[2];
      const float j00 = r[1][0], j01 = r[1][1], j02 = r[1][2];
      const float j10 = r[2][0], j11 = r[2][1], j12 = r[2][2];
      const float j20 = r[3][0], j21 = r[3][1], j22 = r[3][2];
      const float dv = j00 + j11 + j22;
      const float jx = j12 - j21;
      const float jy = j20 - j02;
      const float jz = j01 - j10;
      const float e1 = jy * bz - jz * by;
      const float e2 = jz * bx - jx * bz;
      const float e3 = jx * by - jy * bx;
      ad2 += dv * dv;
      ajx += e1 * e1 + e2 * e2 + e3 * e3;
    }
  }
  if (lane == 0) { red[wv] = ad2; red[8 + wv] = ajx; }
  __syncthreads();
  if (tid == 0) {
    float d = 0.f, jj = 0.f;
#pragma unroll
    for (int w = 0; w < 8; ++w) { d += red[w]; jj += red[8 + w]; }
    part_div2[blockIdx.x] = d;
    part_jxb[blockIdx.x] = jj;
  }
}

// ---------------------------------------------------------------------------
// bc: same structure, 1 state (primal only), z = 0 plane.
// ---------------------------------------------------------------------------
__global__ __launch_bounds__(512, 4) void bc_kernel(
    const float* __restrict__ x0, const float* __restrict__ y0,
    const float* __restrict__ bx0, const float* __restrict__ by0,
    const float* __restrict__ bz0,
    const float* __restrict__ lb, const float* __restrict__ ub,
    const float* __restrict__ W0, const float* __restrict__ b0,
    const float* __restrict__ b1, const float* __restrict__ b2,
    const float* __restrict__ b3, const float* __restrict__ b4,
    const float* __restrict__ b5,
    const short* __restrict__ Wt,
    const float* __restrict__ W6, const float* __restrict__ b6,
    float* __restrict__ part_bc)
{
  __shared__ short act[32 * 256];  // 16 KB
  __shared__ float red[8];
  const int tid = threadIdx.x;
  const int lane = tid & 63;
  const int wv = tid >> 6;
  const int c = lane & 15;
  const int kg = lane >> 4;
  const int pbase = (wv >> 2) * 16;
  const int nbase = (wv & 3) * 64;

  const float lbx = lb[0], lby = lb[1], lbz = lb[2];
  const float sx = 2.f / (ub[0] - lbx);
  const float sy = 2.f / (ub[1] - lby);
  const float sz = 2.f / (ub[2] - lbz);

  // ---- layer 0 ----
  {
    const int p = tid >> 4;
    const int pt = blockIdx.x * 32 + p;
    const int n0 = (tid & 15) * 16;
    const float hx = (x0[pt] - lbx) * sx - 1.f;
    const float hy = (y0[pt] - lby) * sy - 1.f;
    const float hz = (0.f - lbz) * sz - 1.f;
    bf16x8 buf[2];
#pragma unroll
    for (int j = 0; j < 16; ++j) {
      const int n = n0 + j;
      const float z = b0[n] + hx * W0[n] + hy * W0[256 + n] + hz * W0[512 + n];
      buf[j >> 3][j & 7] = f2b(tanhf(z));
    }
    *(bf16x8*)&act[swzp(p, n0)]     = buf[0];
    *(bf16x8*)&act[swzp(p, n0 + 8)] = buf[1];
  }
  __syncthreads();

  const int prow = pbase + c;
  const float* const bsArr[5] = {b1, b2, b3, b4, b5};

#pragma unroll
  for (int layer = 0; layer < 5; ++layer) {
    const short* Wl = Wt + layer * 65536;
    const float* bl = bsArr[layer];
    const short* wrow[4];
#pragma unroll
    for (int t = 0; t < 4; ++t) wrow[t] = Wl + (nbase + t * 16 + c) * 256;

    f32x4 acc[4];
#pragma unroll
    for (int t = 0; t < 4; ++t) acc[t] = (f32x4){0.f, 0.f, 0.f, 0.f};

#pragma unroll
    for (int ks = 0; ks < 8; ++ks) {
      const int k0 = ks * 32 + kg * 8;
      const bf16x8 a0 = *(const bf16x8*)&act[swzp(prow, k0)];
#pragma unroll
      for (int t = 0; t < 4; ++t) {
        const bf16x8 bb = *(const bf16x8*)(wrow[t] + k0);
        acc[t] = __builtin_amdgcn_mfma_f32_16x16x32_bf16(a0, bb, acc[t], 0, 0, 0);
      }
    }
    __syncthreads();
#pragma unroll
    for (int t = 0; t < 4; ++t) {
      const int n = nbase + t * 16 + c;
      const float bias = bl[n];
#pragma unroll
      for (int r = 0; r < 4; ++r) {
        const int p = pbase + kg * 4 + r;
        act[swzp(p, n)] = f2b(tanhf(acc[t][r] + bias));
      }
    }
    __syncthreads();
  }

  // ---- layer 6 + BC loss ----
  float abc = 0.f;
#pragma unroll
  for (int i = 0; i < 4; ++i) {
    const int p = wv * 4 + i;
    const int k0 = lane * 4;
    float r[3] = {};
    const bf16x4 hv = *(const bf16x4*)&act[swzp(p, k0)];
#pragma unroll
    for (int e = 0; e < 4; ++e) {
      const float h = b2f(hv[e]);
      const float* w6r = W6 + (k0 + e) * 3;
      r[0] = fmaf(h, w6r[0], r[0]);
      r[1] = fmaf(h, w6r[1], r[1]);
      r[2] = fmaf(h, w6r[2], r[2]);
    }
#pragma unroll
    for (int o = 0; o < 3; ++o) {
      float v = r[o];
      for (int off = 32; off > 0; off >>= 1) v += __shfl_down(v, off);
      r[o] = v;
    }
    if (lane == 0) {
      const int pt = blockIdx.x * 32 + p;
      const float ex = r[0] + b6[0] - bx0[pt];
      const float ey = r[1] + b6[1] - by0[pt];
      const float ez = r[2] + b6[2] - bz0[pt];
      abc += ex * ex + ey * ey + ez * ez;
    }
  }
  if (lane == 0) red[wv] = abc;
  __syncthreads();
  if (tid == 0) {
    float b = 0.f;
#pragma unroll
    for (int w = 0; w < 8; ++w) b += red[w];
    part_bc[blockIdx.x] = b;
  }
}

// ---------------------------------------------------------------------------
// reduce: parts[0,1024)=div2, [1024,2048)=jxb, [2048,2560)=bc
// ---------------------------------------------------------------------------
__global__ void reduce_kernel(const float* __restrict__ parts, float* __restrict__ out)
{
  __shared__ float sdata[12];
  const int tid = threadIdx.x, lane = tid & 63, wv = tid >> 6;
  float d = 0.f, j = 0.f, b = 0.f;
  for (int i = tid; i < 1024; i += 256) { d += parts[i]; j += parts[1024 + i]; }
  for (int i = tid; i < 512; i += 256) b += parts[2048 + i];
  for (int off = 32; off > 0; off >>= 1) {
    d += __shfl_down(d, off);
    j += __shfl_down(j, off);
    b += __shfl_down(b, off);
  }
  if (lane == 0) {
    sdata[wv * 3 + 0] = d;
    sdata[wv * 3 + 1] = j;
    sdata[wv * 3 + 2] = b;
  }
  __syncthreads();
  if (tid == 0) {
    float sd = 0.f, sj = 0.f, sb = 0.f;
    for (int w = 0; w < 4; ++w) {
      sd += sdata[w * 3 + 0];
      sj += sdata[w * 3 + 1];
      sb += sdata[w * 3 + 2];
    }
    out[0] = sb / (float)NPT0 + sd / (float)NPTF + sj / (float)NPTF;
  }
}

extern "C" void kernel_launch(void* const* d_in, const int* in_sizes, int n_in,
                              void* d_out, int out_size, void* d_ws, size_t ws_size,
                              hipStream_t stream)
{
  const float* x0    = (const float*)d_in[0];
  const float* y0    = (const float*)d_in[1];
  const float* bx0   = (const float*)d_in[2];
  const float* by0   = (const float*)d_in[3];
  const float* bz0   = (const float*)d_in[4];
  const float* xyz_f = (const float*)d_in[5];
  const float* lb    = (const float*)d_in[6];
  const float* ub    = (const float*)d_in[7];
  const float* W0 = (const float*)d_in[8];
  const float* b0 = (const float*)d_in[9];
  const float* W1 = (const float*)d_in[10];
  const float* b1 = (const float*)d_in[11];
  const float* W2 = (const float*)d_in[12];
  const float* b2 = (const float*)d_in[13];
  const float* W3 = (const float*)d_in[14];
  const float* b3 = (const float*)d_in[15];
  const float* W4 = (const float*)d_in[16];
  const float* b4 = (const float*)d_in[17];
  const float* W5 = (const float*)d_in[18];
  const float* b5 = (const float*)d_in[19];
  const float* W6 = (const float*)d_in[20];
  const float* b6 = (const float*)d_in[21];

  short* Wt = (short*)d_ws;                                   // 655360 B
  float* parts = (float*)((char*)d_ws + 5 * 65536 * sizeof(short));
  float* p_div2 = parts;          // 1024
  float* p_jxb  = parts + 1024;   // 1024
  float* p_bc   = parts + 2048;   // 512

  prep_kernel<<<1280, 256, 0, stream>>>(W1, W2, W3, W4, W5, Wt);
  field_kernel<<<1024, 512, 0, stream>>>(xyz_f, lb, ub, W0, b0,
      b1, b2, b3, b4, b5, Wt, W6, b6, p_div2, p_jxb);
  bc_kernel<<<512, 512, 0, stream>>>(x0, y0, bx0, by0, bz0, lb, ub, W0, b0,
      b1, b2, b3, b4, b5, Wt, W6, b6, p_bc);
  reduce_kernel<<<1, 256, 0, stream>>>(parts, (float*)d_out);
}

// Round 3
// 288.200 us; speedup vs baseline: 4.7867x; 1.2907x over previous
//
#include <hip/hip_runtime.h>
#include <math.h>

typedef short bf16x8 __attribute__((ext_vector_type(8)));
typedef short bf16x4 __attribute__((ext_vector_type(4)));
typedef float f32x4 __attribute__((ext_vector_type(4)));

#define NPT0 16384
#define NPTF 32768

__device__ __forceinline__ short f2b(float f) {
  union { float f; unsigned u; } v; v.f = f;
  return (short)((v.u + 0x7FFFu + ((v.u >> 16) & 1u)) >> 16);
}
__device__ __forceinline__ float b2f(short s) {
  union { unsigned u; float f; } v;
  v.u = ((unsigned)(unsigned short)s) << 16;
  return v.f;
}
// tanh(z) = 1 - 2/(exp(2z)+1). Saturates correctly at +-1 (exp->inf/0).
__device__ __forceinline__ float tanh_fast(float z) {
  const float e = __expf(2.f * z);
  return 1.f - 2.f * __builtin_amdgcn_rcpf(e + 1.f);
}
// swizzled short-index into one [16][256] bf16 plane (rows 512B apart):
// XOR row-bits into bank bits so stride-512B column reads spread over banks.
__device__ __forceinline__ int swz(int p, int k) {
  int byte = p * 512 + k * 2;
  byte ^= (p & 7) << 4;
  return byte >> 1;
}

// ---------------------------------------------------------------------------
// prep: W1..W5 fp32 [k][n] -> Wt bf16 [layer][n][k]
// ---------------------------------------------------------------------------
__global__ void prep_kernel(const float* __restrict__ W1, const float* __restrict__ W2,
                            const float* __restrict__ W3, const float* __restrict__ W4,
                            const float* __restrict__ W5, short* __restrict__ Wt)
{
  const int layer = blockIdx.x >> 8;
  const float* src = layer == 0 ? W1 : layer == 1 ? W2 : layer == 2 ? W3
                   : layer == 3 ? W4 : W5;
  const int i = (blockIdx.x & 255) * 256 + threadIdx.x;
  const int n = i >> 8, k = i & 255;
  Wt[layer * 65536 + i] = f2b(src[k * 256 + n]);
}

// ---------------------------------------------------------------------------
// field: 16 pts/block, 4 waves; wave wv owns n-cols [wv*64, wv*64+64).
// MFMA: A = Wt rows (n), B = act cols (p)  ->  D[n][p], col=lane&15=p.
// States: 0=h, 1=dx, 2=dy, 3=dz.
// ---------------------------------------------------------------------------
__global__ __launch_bounds__(256, 4) void field_kernel(
    const float* __restrict__ xyz_f,
    const float* __restrict__ lb, const float* __restrict__ ub,
    const float* __restrict__ W0, const float* __restrict__ b0,
    const float* __restrict__ b1, const float* __restrict__ b2,
    const float* __restrict__ b3, const float* __restrict__ b4,
    const float* __restrict__ b5,
    const short* __restrict__ Wt,
    const float* __restrict__ W6, const float* __restrict__ b6,
    float* __restrict__ part_div2, float* __restrict__ part_jxb)
{
  __shared__ short act[4 * 16 * 256];  // 32 KB: 4 state planes of [16][256]
  __shared__ float red[8];
  const int tid = threadIdx.x;
  const int lane = tid & 63;
  const int wv = tid >> 6;       // 0..3
  const int c = lane & 15;
  const int kg = lane >> 4;
  const int nbase = wv * 64;

  const float lbx = lb[0], lby = lb[1], lbz = lb[2];
  const float sx = 2.f / (ub[0] - lbx);
  const float sy = 2.f / (ub[1] - lby);
  const float sz = 2.f / (ub[2] - lbz);

  // ---- layer 0 (3 -> 256): thread t -> point t>>4, 16 neurons ----
  {
    const int p = tid >> 4;
    const int pt = blockIdx.x * 16 + p;
    const int n0 = (tid & 15) * 16;
    const float hx = (xyz_f[pt * 3 + 0] - lbx) * sx - 1.f;
    const float hy = (xyz_f[pt * 3 + 1] - lby) * sy - 1.f;
    const float hz = (xyz_f[pt * 3 + 2] - lbz) * sz - 1.f;
    bf16x8 buf[4][2];
#pragma unroll
    for (int j = 0; j < 16; ++j) {
      const int n = n0 + j;
      const float w0 = W0[n], w1 = W0[256 + n], w2 = W0[512 + n];
      const float z = b0[n] + hx * w0 + hy * w1 + hz * w2;
      const float th = tanh_fast(z);
      const float g = 1.f - th * th;
      buf[0][j >> 3][j & 7] = f2b(th);
      buf[1][j >> 3][j & 7] = f2b(g * sx * w0);
      buf[2][j >> 3][j & 7] = f2b(g * sy * w1);
      buf[3][j >> 3][j & 7] = f2b(g * sz * w2);
    }
#pragma unroll
    for (int s = 0; s < 4; ++s) {
      *(bf16x8*)&act[s * 4096 + swz(p, n0)]     = buf[s][0];
      *(bf16x8*)&act[s * 4096 + swz(p, n0 + 8)] = buf[s][1];
    }
  }
  __syncthreads();

  const float* const bsArr[5] = {b1, b2, b3, b4, b5};
  const short* const wbase = Wt + (nbase + c) * 256;

#pragma unroll
  for (int layer = 0; layer < 5; ++layer) {
    const short* wl = wbase + layer * 65536;

    f32x4 acc[4][4];
#pragma unroll
    for (int s = 0; s < 4; ++s)
#pragma unroll
      for (int t = 0; t < 4; ++t) acc[s][t] = (f32x4){0.f, 0.f, 0.f, 0.f};

#pragma unroll
    for (int ks = 0; ks < 8; ++ks) {
      const int k0 = ks * 32 + kg * 8;
      const int sa = swz(c, k0);
      const bf16x8 a0 = *(const bf16x8*)&act[sa];
      const bf16x8 a1 = *(const bf16x8*)&act[4096 + sa];
      const bf16x8 a2 = *(const bf16x8*)&act[8192 + sa];
      const bf16x8 a3 = *(const bf16x8*)&act[12288 + sa];
#pragma unroll
      for (int t = 0; t < 4; ++t) {
        const bf16x8 w = *(const bf16x8*)(wl + t * 4096 + k0);
        acc[0][t] = __builtin_amdgcn_mfma_f32_16x16x32_bf16(w, a0, acc[0][t], 0, 0, 0);
        acc[1][t] = __builtin_amdgcn_mfma_f32_16x16x32_bf16(w, a1, acc[1][t], 0, 0, 0);
        acc[2][t] = __builtin_amdgcn_mfma_f32_16x16x32_bf16(w, a2, acc[2][t], 0, 0, 0);
        acc[3][t] = __builtin_amdgcn_mfma_f32_16x16x32_bf16(w, a3, acc[3][t], 0, 0, 0);
      }
    }
    __syncthreads();  // all LDS reads of layer L done

    // epilogue: lane holds p=c, n = nbase + t*16 + kg*4 + r (r consecutive)
    const float* bl = bsArr[layer];
#pragma unroll
    for (int t = 0; t < 4; ++t) {
      const int n0 = nbase + t * 16 + kg * 4;
      const f32x4 bias = *(const f32x4*)(bl + n0);
      bf16x4 o0, o1, o2, o3;
#pragma unroll
      for (int r = 0; r < 4; ++r) {
        const float th = tanh_fast(acc[0][t][r] + bias[r]);
        const float g = 1.f - th * th;
        o0[r] = f2b(th);
        o1[r] = f2b(g * acc[1][t][r]);
        o2[r] = f2b(g * acc[2][t][r]);
        o3[r] = f2b(g * acc[3][t][r]);
      }
      const int sw = swz(c, n0);
      *(bf16x4*)&act[sw]         = o0;
      *(bf16x4*)&act[4096 + sw]  = o1;
      *(bf16x4*)&act[8192 + sw]  = o2;
      *(bf16x4*)&act[12288 + sw] = o3;
    }
    __syncthreads();  // layer L+1 act complete
  }

  // ---- layer 6 (256 -> 3) + physics: wave wv -> pts wv*4 .. wv*4+3 ----
  float ad2 = 0.f, ajx = 0.f;
#pragma unroll
  for (int i = 0; i < 4; ++i) {
    const int p = wv * 4 + i;
    const int k0 = lane * 4;
    float r[4][3] = {};
#pragma unroll
    for (int s = 0; s < 4; ++s) {
      const bf16x4 hv = *(const bf16x4*)&act[s * 4096 + swz(p, k0)];
#pragma unroll
      for (int e = 0; e < 4; ++e) {
        const float h = b2f(hv[e]);
        const float* w6r = W6 + (k0 + e) * 3;
        r[s][0] = fmaf(h, w6r[0], r[s][0]);
        r[s][1] = fmaf(h, w6r[1], r[s][1]);
        r[s][2] = fmaf(h, w6r[2], r[s][2]);
      }
    }
#pragma unroll
    for (int s = 0; s < 4; ++s)
#pragma unroll
      for (int o = 0; o < 3; ++o) {
        float v = r[s][o];
        for (int off = 32; off > 0; off >>= 1) v += __shfl_down(v, off);
        r[s][o] = v;
      }
    if (lane == 0) {
      const float bx = r[0][0] + b6[0];
      const float by = r[0][1] + b6[1];
      const float bz = r[0][2] + b6[2];
      const float j00 = r[1][0], j01 = r[1][1], j02 = r[1][2];
      const float j10 = r[2][0], j11 = r[2][1], j12 = r[2][2];
      const float j20 = r[3][0], j21 = r[3][1], j22 = r[3][2];
      const float dv = j00 + j11 + j22;
      const float jx = j12 - j21;
      const float jy = j20 - j02;
      const float jz = j01 - j10;
      const float e1 = jy * bz - jz * by;
      const float e2 = jz * bx - jx * bz;
      const float e3 = jx * by - jy * bx;
      ad2 += dv * dv;
      ajx += e1 * e1 + e2 * e2 + e3 * e3;
    }
  }
  if (lane == 0) { red[wv] = ad2; red[4 + wv] = ajx; }
  __syncthreads();
  if (tid == 0) {
    float d = 0.f, jj = 0.f;
#pragma unroll
    for (int w = 0; w < 4; ++w) { d += red[w]; jj += red[4 + w]; }
    part_div2[blockIdx.x] = d;
    part_jxb[blockIdx.x] = jj;
  }
}

// ---------------------------------------------------------------------------
// bc: 16 pts/block, 4 waves, 1 state (z=0 plane). Act tile hoisted to regs
// so the W-load+MFMA+epilogue phase runs barrier-free.
// ---------------------------------------------------------------------------
__global__ __launch_bounds__(256, 4) void bc_kernel(
    const float* __restrict__ x0, const float* __restrict__ y0,
    const float* __restrict__ bx0, const float* __restrict__ by0,
    const float* __restrict__ bz0,
    const float* __restrict__ lb, const float* __restrict__ ub,
    const float* __restrict__ W0, const float* __restrict__ b0,
    const float* __restrict__ b1, const float* __restrict__ b2,
    const float* __restrict__ b3, const float* __restrict__ b4,
    const float* __restrict__ b5,
    const short* __restrict__ Wt,
    const float* __restrict__ W6, const float* __restrict__ b6,
    float* __restrict__ part_bc)
{
  __shared__ short act[16 * 256];  // 8 KB
  __shared__ float red[4];
  const int tid = threadIdx.x;
  const int lane = tid & 63;
  const int wv = tid >> 6;
  const int c = lane & 15;
  const int kg = lane >> 4;
  const int nbase = wv * 64;

  const float lbx = lb[0], lby = lb[1], lbz = lb[2];
  const float sx = 2.f / (ub[0] - lbx);
  const float sy = 2.f / (ub[1] - lby);
  const float sz = 2.f / (ub[2] - lbz);

  // ---- layer 0 ----
  {
    const int p = tid >> 4;
    const int pt = blockIdx.x * 16 + p;
    const int n0 = (tid & 15) * 16;
    const float hx = (x0[pt] - lbx) * sx - 1.f;
    const float hy = (y0[pt] - lby) * sy - 1.f;
    const float hz = (0.f - lbz) * sz - 1.f;
    bf16x8 buf[2];
#pragma unroll
    for (int j = 0; j < 16; ++j) {
      const int n = n0 + j;
      const float z = b0[n] + hx * W0[n] + hy * W0[256 + n] + hz * W0[512 + n];
      buf[j >> 3][j & 7] = f2b(tanh_fast(z));
    }
    *(bf16x8*)&act[swz(p, n0)]     = buf[0];
    *(bf16x8*)&act[swz(p, n0 + 8)] = buf[1];
  }
  __syncthreads();

  const float* const bsArr[5] = {b1, b2, b3, b4, b5};
  const short* const wbase = Wt + (nbase + c) * 256;

#pragma unroll
  for (int layer = 0; layer < 5; ++layer) {
    const short* wl = wbase + layer * 65536;

    // hoist act reads (32 VGPRs)
    bf16x8 a[8];
#pragma unroll
    for (int ks = 0; ks < 8; ++ks) a[ks] = *(const bf16x8*)&act[swz(c, ks * 32 + kg * 8)];
    __syncthreads();  // reads done -> writes below are safe

    f32x4 acc[4];
#pragma unroll
    for (int t = 0; t < 4; ++t) acc[t] = (f32x4){0.f, 0.f, 0.f, 0.f};

#pragma unroll
    for (int ks = 0; ks < 8; ++ks) {
      const int k0 = ks * 32 + kg * 8;
#pragma unroll
      for (int t = 0; t < 4; ++t) {
        const bf16x8 w = *(const bf16x8*)(wl + t * 4096 + k0);
        acc[t] = __builtin_amdgcn_mfma_f32_16x16x32_bf16(w, a[ks], acc[t], 0, 0, 0);
      }
    }

    const float* bl = bsArr[layer];
#pragma unroll
    for (int t = 0; t < 4; ++t) {
      const int n0 = nbase + t * 16 + kg * 4;
      const f32x4 bias = *(const f32x4*)(bl + n0);
      bf16x4 o;
#pragma unroll
      for (int r = 0; r < 4; ++r) o[r] = f2b(tanh_fast(acc[t][r] + bias[r]));
      *(bf16x4*)&act[swz(c, n0)] = o;
    }
    __syncthreads();  // act[L+1] complete
  }

  // ---- layer 6 + BC loss ----
  float abc = 0.f;
#pragma unroll
  for (int i = 0; i < 4; ++i) {
    const int p = wv * 4 + i;
    const int k0 = lane * 4;
    float r[3] = {};
    const bf16x4 hv = *(const bf16x4*)&act[swz(p, k0)];
#pragma unroll
    for (int e = 0; e < 4; ++e) {
      const float h = b2f(hv[e]);
      const float* w6r = W6 + (k0 + e) * 3;
      r[0] = fmaf(h, w6r[0], r[0]);
      r[1] = fmaf(h, w6r[1], r[1]);
      r[2] = fmaf(h, w6r[2], r[2]);
    }
#pragma unroll
    for (int o = 0; o < 3; ++o) {
      float v = r[o];
      for (int off = 32; off > 0; off >>= 1) v += __shfl_down(v, off);
      r[o] = v;
    }
    if (lane == 0) {
      const int pt = blockIdx.x * 16 + p;
      const float ex = r[0] + b6[0] - bx0[pt];
      const float ey = r[1] + b6[1] - by0[pt];
      const float ez = r[2] + b6[2] - bz0[pt];
      abc += ex * ex + ey * ey + ez * ez;
    }
  }
  if (lane == 0) red[wv] = abc;
  __syncthreads();
  if (tid == 0) {
    float b = 0.f;
#pragma unroll
    for (int w = 0; w < 4; ++w) b += red[w];
    part_bc[blockIdx.x] = b;
  }
}

// ---------------------------------------------------------------------------
// reduce: parts[0,2048)=div2, [2048,4096)=jxb, [4096,5120)=bc
// ---------------------------------------------------------------------------
__global__ void reduce_kernel(const float* __restrict__ parts, float* __restrict__ out)
{
  __shared__ float sdata[12];
  const int tid = threadIdx.x, lane = tid & 63, wv = tid >> 6;
  float d = 0.f, j = 0.f, b = 0.f;
  for (int i = tid; i < 2048; i += 256) { d += parts[i]; j += parts[2048 + i]; }
  for (int i = tid; i < 1024; i += 256) b += parts[4096 + i];
  for (int off = 32; off > 0; off >>= 1) {
    d += __shfl_down(d, off);
    j += __shfl_down(j, off);
    b += __shfl_down(b, off);
  }
  if (lane == 0) {
    sdata[wv * 3 + 0] = d;
    sdata[wv * 3 + 1] = j;
    sdata[wv * 3 + 2] = b;
  }
  __syncthreads();
  if (tid == 0) {
    float sd = 0.f, sj = 0.f, sb = 0.f;
    for (int w = 0; w < 4; ++w) {
      sd += sdata[w * 3 + 0];
      sj += sdata[w * 3 + 1];
      sb += sdata[w * 3 + 2];
    }
    out[0] = sb / (float)NPT0 + sd / (float)NPTF + sj / (float)NPTF;
  }
}

extern "C" void kernel_launch(void* const* d_in, const int* in_sizes, int n_in,
                              void* d_out, int out_size, void* d_ws, size_t ws_size,
                              hipStream_t stream)
{
  const float* x0    = (const float*)d_in[0];
  const float* y0    = (const float*)d_in[1];
  const float* bx0   = (const float*)d_in[2];
  const float* by0   = (const float*)d_in[3];
  const float* bz0   = (const float*)d_in[4];
  const float* xyz_f = (const float*)d_in[5];
  const float* lb    = (const float*)d_in[6];
  const float* ub    = (const float*)d_in[7];
  const float* W0 = (const float*)d_in[8];
  const float* b0 = (const float*)d_in[9];
  const float* W1 = (const float*)d_in[10];
  const float* b1 = (const float*)d_in[11];
  const float* W2 = (const float*)d_in[12];
  const float* b2 = (const float*)d_in[13];
  const float* W3 = (const float*)d_in[14];
  const float* b3 = (const float*)d_in[15];
  const float* W4 = (const float*)d_in[16];
  const float* b4 = (const float*)d_in[17];
  const float* W5 = (const float*)d_in[18];
  const float* b5 = (const float*)d_in[19];
  const float* W6 = (const float*)d_in[20];
  const float* b6 = (const float*)d_in[21];

  short* Wt = (short*)d_ws;                                   // 655360 B
  float* parts = (float*)((char*)d_ws + 5 * 65536 * sizeof(short));
  float* p_div2 = parts;          // 2048
  float* p_jxb  = parts + 2048;   // 2048
  float* p_bc   = parts + 4096;   // 1024

  prep_kernel<<<1280, 256, 0, stream>>>(W1, W2, W3, W4, W5, Wt);
  field_kernel<<<2048, 256, 0, stream>>>(xyz_f, lb, ub, W0, b0,
      b1, b2, b3, b4, b5, Wt, W6, b6, p_div2, p_jxb);
  bc_kernel<<<1024, 256, 0, stream>>>(x0, y0, bx0, by0, bz0, lb, ub, W0, b0,
      b1, b2, b3, b4, b5, Wt, W6, b6, p_bc);
  reduce_kernel<<<1, 256, 0, stream>>>(parts, (float*)d_out);
}

// Round 4
// 161.580 us; speedup vs baseline: 8.5378x; 1.7836x over previous
//
#include <hip/hip_runtime.h>
#include <math.h>

typedef short bf16x8 __attribute__((ext_vector_type(8)));
typedef short bf16x4 __attribute__((ext_vector_type(4)));
typedef float f32x4 __attribute__((ext_vector_type(4)));

#define NPT0 16384
#define NPTF 32768

__device__ __forceinline__ short f2b(float f) {
  union { float f; unsigned u; } v; v.f = f;
  return (short)((v.u + 0x7FFFu + ((v.u >> 16) & 1u)) >> 16);
}
__device__ __forceinline__ float b2f(short s) {
  union { unsigned u; float f; } v;
  v.u = ((unsigned)(unsigned short)s) << 16;
  return v.f;
}
// packed bf16 pair: lo = bf16(a), hi = bf16(b)
__device__ __forceinline__ int cvtpk(float a, float b) {
  int r;
  asm("v_cvt_pk_bf16_f32 %0, %1, %2" : "=v"(r) : "v"(a), "v"(b));
  return r;
}
// tanh(z) = 1 - 2/(exp(2z)+1). Saturates correctly at +-1 (exp->inf/0).
__device__ __forceinline__ float tanh_fast(float z) {
  const float e = __expf(2.f * z);
  return 1.f - 2.f * __builtin_amdgcn_rcpf(e + 1.f);
}
// swizzled short-index into one [16][256] bf16 plane (rows 512B apart):
// XOR row-bits into bank bits so stride-512B column reads spread over banks.
__device__ __forceinline__ int swz(int p, int k) {
  int byte = p * 512 + k * 2;
  byte ^= (p & 7) << 4;
  return byte >> 1;
}

// ---------------------------------------------------------------------------
// prep: W1..W5 fp32 [k][n] -> packed MFMA A-fragment chunks.
// Chunk grid [layer][nt(16)][ks(8)], chunk = 512 shorts, element (l,e):
//   n = nt*16 + (l&15), k = ks*32 + (l>>4)*8 + e
// A wave loads one chunk as a single coalesced 1KB global_load_dwordx4.
// ---------------------------------------------------------------------------
__global__ void prep_kernel(const float* __restrict__ W1, const float* __restrict__ W2,
                            const float* __restrict__ W3, const float* __restrict__ W4,
                            const float* __restrict__ W5, short* __restrict__ Wt)
{
  const int i = blockIdx.x * 256 + threadIdx.x;   // 0..327679
  const int layer = i >> 16;
  const float* src = layer == 0 ? W1 : layer == 1 ? W2 : layer == 2 ? W3
                   : layer == 3 ? W4 : W5;
  const int w  = i & 65535;
  const int nt = w >> 12;
  const int ks = (w >> 9) & 7;
  const int l  = (w >> 3) & 63;
  const int e  = w & 7;
  const int n  = nt * 16 + (l & 15);
  const int k  = ks * 32 + (l >> 4) * 8 + e;
  Wt[i] = f2b(src[k * 256 + n]);
}

// ---------------------------------------------------------------------------
// field: 16 pts/block, 4 waves; wave wv owns n-cols [wv*64, wv*64+64).
// MFMA: A = W chunk (rows n), B = act (cols p) -> D[n][p], col=lane&15=p.
// States: 0=h, 1=dx, 2=dy, 3=dz.
// ---------------------------------------------------------------------------
__global__ __launch_bounds__(256, 3) void field_kernel(
    const float* __restrict__ xyz_f,
    const float* __restrict__ lb, const float* __restrict__ ub,
    const float* __restrict__ W0, const float* __restrict__ b0,
    const float* __restrict__ b1, const float* __restrict__ b2,
    const float* __restrict__ b3, const float* __restrict__ b4,
    const float* __restrict__ b5,
    const short* __restrict__ Wt,
    const float* __restrict__ W6, const float* __restrict__ b6,
    float* __restrict__ part_div2, float* __restrict__ part_jxb)
{
  __shared__ short act[4 * 16 * 256];  // 32 KB: 4 state planes of [16][256]
  __shared__ float red[8];
  const int tid = threadIdx.x;
  const int lane = tid & 63;
  const int wv = tid >> 6;       // 0..3
  const int c = lane & 15;
  const int kg = lane >> 4;
  const int nbase = wv * 64;

  const float lbx = lb[0], lby = lb[1], lbz = lb[2];
  const float sx = 2.f / (ub[0] - lbx);
  const float sy = 2.f / (ub[1] - lby);
  const float sz = 2.f / (ub[2] - lbz);

  // ---- layer 0 (3 -> 256): thread t -> point t>>4, 16 neurons ----
  {
    const int p = tid >> 4;
    const int pt = blockIdx.x * 16 + p;
    const int n0 = (tid & 15) * 16;
    const float hx = (xyz_f[pt * 3 + 0] - lbx) * sx - 1.f;
    const float hy = (xyz_f[pt * 3 + 1] - lby) * sy - 1.f;
    const float hz = (xyz_f[pt * 3 + 2] - lbz) * sz - 1.f;
    float th[16], vx[16], vy[16], vz[16];
#pragma unroll
    for (int j = 0; j < 16; ++j) {
      const int n = n0 + j;
      const float w0 = W0[n], w1 = W0[256 + n], w2 = W0[512 + n];
      const float z = b0[n] + hx * w0 + hy * w1 + hz * w2;
      const float t = tanh_fast(z);
      const float g = 1.f - t * t;
      th[j] = t;
      vx[j] = g * sx * w0;
      vy[j] = g * sy * w1;
      vz[j] = g * sz * w2;
    }
#pragma unroll
    for (int half = 0; half < 2; ++half) {
      const int j0 = half * 8;
      int4 o0, o1, o2, o3;
      o0.x = cvtpk(th[j0+0], th[j0+1]); o0.y = cvtpk(th[j0+2], th[j0+3]);
      o0.z = cvtpk(th[j0+4], th[j0+5]); o0.w = cvtpk(th[j0+6], th[j0+7]);
      o1.x = cvtpk(vx[j0+0], vx[j0+1]); o1.y = cvtpk(vx[j0+2], vx[j0+3]);
      o1.z = cvtpk(vx[j0+4], vx[j0+5]); o1.w = cvtpk(vx[j0+6], vx[j0+7]);
      o2.x = cvtpk(vy[j0+0], vy[j0+1]); o2.y = cvtpk(vy[j0+2], vy[j0+3]);
      o2.z = cvtpk(vy[j0+4], vy[j0+5]); o2.w = cvtpk(vy[j0+6], vy[j0+7]);
      o3.x = cvtpk(vz[j0+0], vz[j0+1]); o3.y = cvtpk(vz[j0+2], vz[j0+3]);
      o3.z = cvtpk(vz[j0+4], vz[j0+5]); o3.w = cvtpk(vz[j0+6], vz[j0+7]);
      const int sw = swz(p, n0 + j0);
      *(int4*)&act[sw]         = o0;
      *(int4*)&act[4096 + sw]  = o1;
      *(int4*)&act[8192 + sw]  = o2;
      *(int4*)&act[12288 + sw] = o3;
    }
  }
  __syncthreads();

  const float* const bsArr[5] = {b1, b2, b3, b4, b5};

#pragma unroll
  for (int layer = 0; layer < 5; ++layer) {
    // per-wave packed W chunk pointers: tile t chunk at +t*4096, step ks at +ks*512
    const short* wt0 = Wt + layer * 65536 + (wv * 4 + 0) * 4096 + lane * 8;
    const short* wt1 = wt0 + 4096;
    const short* wt2 = wt0 + 8192;
    const short* wt3 = wt0 + 12288;

    f32x4 acc[4][4];
#pragma unroll
    for (int s = 0; s < 4; ++s)
#pragma unroll
      for (int t = 0; t < 4; ++t) acc[s][t] = (f32x4){0.f, 0.f, 0.f, 0.f};

#pragma unroll
    for (int ks = 0; ks < 8; ++ks) {
      const int sa = swz(c, ks * 32 + kg * 8);
      const bf16x8 a0 = *(const bf16x8*)&act[sa];
      const bf16x8 a1 = *(const bf16x8*)&act[4096 + sa];
      const bf16x8 a2 = *(const bf16x8*)&act[8192 + sa];
      const bf16x8 a3 = *(const bf16x8*)&act[12288 + sa];
      const bf16x8 w0 = *(const bf16x8*)(wt0 + ks * 512);
      const bf16x8 w1 = *(const bf16x8*)(wt1 + ks * 512);
      const bf16x8 w2 = *(const bf16x8*)(wt2 + ks * 512);
      const bf16x8 w3 = *(const bf16x8*)(wt3 + ks * 512);
      acc[0][0] = __builtin_amdgcn_mfma_f32_16x16x32_bf16(w0, a0, acc[0][0], 0, 0, 0);
      acc[1][0] = __builtin_amdgcn_mfma_f32_16x16x32_bf16(w0, a1, acc[1][0], 0, 0, 0);
      acc[2][0] = __builtin_amdgcn_mfma_f32_16x16x32_bf16(w0, a2, acc[2][0], 0, 0, 0);
      acc[3][0] = __builtin_amdgcn_mfma_f32_16x16x32_bf16(w0, a3, acc[3][0], 0, 0, 0);
      acc[0][1] = __builtin_amdgcn_mfma_f32_16x16x32_bf16(w1, a0, acc[0][1], 0, 0, 0);
      acc[1][1] = __builtin_amdgcn_mfma_f32_16x16x32_bf16(w1, a1, acc[1][1], 0, 0, 0);
      acc[2][1] = __builtin_amdgcn_mfma_f32_16x16x32_bf16(w1, a2, acc[2][1], 0, 0, 0);
      acc[3][1] = __builtin_amdgcn_mfma_f32_16x16x32_bf16(w1, a3, acc[3][1], 0, 0, 0);
      acc[0][2] = __builtin_amdgcn_mfma_f32_16x16x32_bf16(w2, a0, acc[0][2], 0, 0, 0);
      acc[1][2] = __builtin_amdgcn_mfma_f32_16x16x32_bf16(w2, a1, acc[1][2], 0, 0, 0);
      acc[2][2] = __builtin_amdgcn_mfma_f32_16x16x32_bf16(w2, a2, acc[2][2], 0, 0, 0);
      acc[3][2] = __builtin_amdgcn_mfma_f32_16x16x32_bf16(w2, a3, acc[3][2], 0, 0, 0);
      acc[0][3] = __builtin_amdgcn_mfma_f32_16x16x32_bf16(w3, a0, acc[0][3], 0, 0, 0);
      acc[1][3] = __builtin_amdgcn_mfma_f32_16x16x32_bf16(w3, a1, acc[1][3], 0, 0, 0);
      acc[2][3] = __builtin_amdgcn_mfma_f32_16x16x32_bf16(w3, a2, acc[2][3], 0, 0, 0);
      acc[3][3] = __builtin_amdgcn_mfma_f32_16x16x32_bf16(w3, a3, acc[3][3], 0, 0, 0);
    }
    __syncthreads();  // all LDS reads of layer L done

    // epilogue: lane holds p=c, n = nbase + t*16 + kg*4 + r (r consecutive)
    const float* bl = bsArr[layer];
#pragma unroll
    for (int t = 0; t < 4; ++t) {
      const int n0 = nbase + t * 16 + kg * 4;
      const f32x4 bias = *(const f32x4*)(bl + n0);
      float th[4], g[4];
#pragma unroll
      for (int r = 0; r < 4; ++r) {
        th[r] = tanh_fast(acc[0][t][r] + bias[r]);
        g[r] = 1.f - th[r] * th[r];
      }
      int2 o0, o1, o2, o3;
      o0.x = cvtpk(th[0], th[1]);
      o0.y = cvtpk(th[2], th[3]);
      o1.x = cvtpk(g[0] * acc[1][t][0], g[1] * acc[1][t][1]);
      o1.y = cvtpk(g[2] * acc[1][t][2], g[3] * acc[1][t][3]);
      o2.x = cvtpk(g[0] * acc[2][t][0], g[1] * acc[2][t][1]);
      o2.y = cvtpk(g[2] * acc[2][t][2], g[3] * acc[2][t][3]);
      o3.x = cvtpk(g[0] * acc[3][t][0], g[1] * acc[3][t][1]);
      o3.y = cvtpk(g[2] * acc[3][t][2], g[3] * acc[3][t][3]);
      const int sw = swz(c, n0);
      *(int2*)&act[sw]         = o0;
      *(int2*)&act[4096 + sw]  = o1;
      *(int2*)&act[8192 + sw]  = o2;
      *(int2*)&act[12288 + sw] = o3;
    }
    __syncthreads();  // layer L+1 act complete
  }

  // ---- layer 6 (256 -> 3) + physics: wave wv -> pts wv*4 .. wv*4+3 ----
  float ad2 = 0.f, ajx = 0.f;
#pragma unroll
  for (int i = 0; i < 4; ++i) {
    const int p = wv * 4 + i;
    const int k0 = lane * 4;
    float r[4][3] = {};
#pragma unroll
    for (int s = 0; s < 4; ++s) {
      const bf16x4 hv = *(const bf16x4*)&act[s * 4096 + swz(p, k0)];
#pragma unroll
      for (int e = 0; e < 4; ++e) {
        const float h = b2f(hv[e]);
        const float* w6r = W6 + (k0 + e) * 3;
        r[s][0] = fmaf(h, w6r[0], r[s][0]);
        r[s][1] = fmaf(h, w6r[1], r[s][1]);
        r[s][2] = fmaf(h, w6r[2], r[s][2]);
      }
    }
#pragma unroll
    for (int s = 0; s < 4; ++s)
#pragma unroll
      for (int o = 0; o < 3; ++o) {
        float v = r[s][o];
        for (int off = 32; off > 0; off >>= 1) v += __shfl_down(v, off);
        r[s][o] = v;
      }
    if (lane == 0) {
      const float bx = r[0][0] + b6[0];
      const float by = r[0][1] + b6[1];
      const float bz = r[0][2] + b6[2];
      const float j00 = r[1][0], j01 = r[1][1], j02 = r[1][2];
      const float j10 = r[2][0], j11 = r[2][1], j12 = r[2][2];
      const float j20 = r[3][0], j21 = r[3][1], j22 = r[3][2];
      const float dv = j00 + j11 + j22;
      const float jx = j12 - j21;
      const float jy = j20 - j02;
      const float jz = j01 - j10;
      const float e1 = jy * bz - jz * by;
      const float e2 = jz * bx - jx * bz;
      const float e3 = jx * by - jy * bx;
      ad2 += dv * dv;
      ajx += e1 * e1 + e2 * e2 + e3 * e3;
    }
  }
  if (lane == 0) { red[wv] = ad2; red[4 + wv] = ajx; }
  __syncthreads();
  if (tid == 0) {
    float d = 0.f, jj = 0.f;
#pragma unroll
    for (int w = 0; w < 4; ++w) { d += red[w]; jj += red[4 + w]; }
    part_div2[blockIdx.x] = d;
    part_jxb[blockIdx.x] = jj;
  }
}

// ---------------------------------------------------------------------------
// bc: 16 pts/block, 4 waves, 1 state (z=0 plane). Act tile hoisted to regs
// so the W-load+MFMA+epilogue phase runs barrier-free.
// ---------------------------------------------------------------------------
__global__ __launch_bounds__(256, 4) void bc_kernel(
    const float* __restrict__ x0, const float* __restrict__ y0,
    const float* __restrict__ bx0, const float* __restrict__ by0,
    const float* __restrict__ bz0,
    const float* __restrict__ lb, const float* __restrict__ ub,
    const float* __restrict__ W0, const float* __restrict__ b0,
    const float* __restrict__ b1, const float* __restrict__ b2,
    const float* __restrict__ b3, const float* __restrict__ b4,
    const float* __restrict__ b5,
    const short* __restrict__ Wt,
    const float* __restrict__ W6, const float* __restrict__ b6,
    float* __restrict__ part_bc)
{
  __shared__ short act[16 * 256];  // 8 KB
  __shared__ float red[4];
  const int tid = threadIdx.x;
  const int lane = tid & 63;
  const int wv = tid >> 6;
  const int c = lane & 15;
  const int kg = lane >> 4;
  const int nbase = wv * 64;

  const float lbx = lb[0], lby = lb[1], lbz = lb[2];
  const float sx = 2.f / (ub[0] - lbx);
  const float sy = 2.f / (ub[1] - lby);
  const float sz = 2.f / (ub[2] - lbz);

  // ---- layer 0 ----
  {
    const int p = tid >> 4;
    const int pt = blockIdx.x * 16 + p;
    const int n0 = (tid & 15) * 16;
    const float hx = (x0[pt] - lbx) * sx - 1.f;
    const float hy = (y0[pt] - lby) * sy - 1.f;
    const float hz = (0.f - lbz) * sz - 1.f;
    float th[16];
#pragma unroll
    for (int j = 0; j < 16; ++j) {
      const int n = n0 + j;
      const float z = b0[n] + hx * W0[n] + hy * W0[256 + n] + hz * W0[512 + n];
      th[j] = tanh_fast(z);
    }
#pragma unroll
    for (int half = 0; half < 2; ++half) {
      const int j0 = half * 8;
      int4 o;
      o.x = cvtpk(th[j0+0], th[j0+1]); o.y = cvtpk(th[j0+2], th[j0+3]);
      o.z = cvtpk(th[j0+4], th[j0+5]); o.w = cvtpk(th[j0+6], th[j0+7]);
      *(int4*)&act[swz(p, n0 + j0)] = o;
    }
  }
  __syncthreads();

  const float* const bsArr[5] = {b1, b2, b3, b4, b5};

#pragma unroll
  for (int layer = 0; layer < 5; ++layer) {
    const short* wt0 = Wt + layer * 65536 + (wv * 4 + 0) * 4096 + lane * 8;

    // hoist act reads (32 VGPRs)
    bf16x8 a[8];
#pragma unroll
    for (int ks = 0; ks < 8; ++ks) a[ks] = *(const bf16x8*)&act[swz(c, ks * 32 + kg * 8)];
    __syncthreads();  // reads done -> writes below are safe

    f32x4 acc[4];
#pragma unroll
    for (int t = 0; t < 4; ++t) acc[t] = (f32x4){0.f, 0.f, 0.f, 0.f};

#pragma unroll
    for (int ks = 0; ks < 8; ++ks) {
#pragma unroll
      for (int t = 0; t < 4; ++t) {
        const bf16x8 w = *(const bf16x8*)(wt0 + t * 4096 + ks * 512);
        acc[t] = __builtin_amdgcn_mfma_f32_16x16x32_bf16(w, a[ks], acc[t], 0, 0, 0);
      }
    }

    const float* bl = bsArr[layer];
#pragma unroll
    for (int t = 0; t < 4; ++t) {
      const int n0 = nbase + t * 16 + kg * 4;
      const f32x4 bias = *(const f32x4*)(bl + n0);
      float th[4];
#pragma unroll
      for (int r = 0; r < 4; ++r) th[r] = tanh_fast(acc[t][r] + bias[r]);
      int2 o;
      o.x = cvtpk(th[0], th[1]);
      o.y = cvtpk(th[2], th[3]);
      *(int2*)&act[swz(c, n0)] = o;
    }
    __syncthreads();  // act[L+1] complete
  }

  // ---- layer 6 + BC loss ----
  float abc = 0.f;
#pragma unroll
  for (int i = 0; i < 4; ++i) {
    const int p = wv * 4 + i;
    const int k0 = lane * 4;
    float r[3] = {};
    const bf16x4 hv = *(const bf16x4*)&act[swz(p, k0)];
#pragma unroll
    for (int e = 0; e < 4; ++e) {
      const float h = b2f(hv[e]);
      const float* w6r = W6 + (k0 + e) * 3;
      r[0] = fmaf(h, w6r[0], r[0]);
      r[1] = fmaf(h, w6r[1], r[1]);
      r[2] = fmaf(h, w6r[2], r[2]);
    }
#pragma unroll
    for (int o = 0; o < 3; ++o) {
      float v = r[o];
      for (int off = 32; off > 0; off >>= 1) v += __shfl_down(v, off);
      r[o] = v;
    }
    if (lane == 0) {
      const int pt = blockIdx.x * 16 + p;
      const float ex = r[0] + b6[0] - bx0[pt];
      const float ey = r[1] + b6[1] - by0[pt];
      const float ez = r[2] + b6[2] - bz0[pt];
      abc += ex * ex + ey * ey + ez * ez;
    }
  }
  if (lane == 0) red[wv] = abc;
  __syncthreads();
  if (tid == 0) {
    float b = 0.f;
#pragma unroll
    for (int w = 0; w < 4; ++w) b += red[w];
    part_bc[blockIdx.x] = b;
  }
}

// ---------------------------------------------------------------------------
// reduce: parts[0,2048)=div2, [2048,4096)=jxb, [4096,5120)=bc
// ---------------------------------------------------------------------------
__global__ void reduce_kernel(const float* __restrict__ parts, float* __restrict__ out)
{
  __shared__ float sdata[12];
  const int tid = threadIdx.x, lane = tid & 63, wv = tid >> 6;
  float d = 0.f, j = 0.f, b = 0.f;
  for (int i = tid; i < 2048; i += 256) { d += parts[i]; j += parts[2048 + i]; }
  for (int i = tid; i < 1024; i += 256) b += parts[4096 + i];
  for (int off = 32; off > 0; off >>= 1) {
    d += __shfl_down(d, off);
    j += __shfl_down(j, off);
    b += __shfl_down(b, off);
  }
  if (lane == 0) {
    sdata[wv * 3 + 0] = d;
    sdata[wv * 3 + 1] = j;
    sdata[wv * 3 + 2] = b;
  }
  __syncthreads();
  if (tid == 0) {
    float sd = 0.f, sj = 0.f, sb = 0.f;
    for (int w = 0; w < 4; ++w) {
      sd += sdata[w * 3 + 0];
      sj += sdata[w * 3 + 1];
      sb += sdata[w * 3 + 2];
    }
    out[0] = sb / (float)NPT0 + sd / (float)NPTF + sj / (float)NPTF;
  }
}

extern "C" void kernel_launch(void* const* d_in, const int* in_sizes, int n_in,
                              void* d_out, int out_size, void* d_ws, size_t ws_size,
                              hipStream_t stream)
{
  const float* x0    = (const float*)d_in[0];
  const float* y0    = (const float*)d_in[1];
  const float* bx0   = (const float*)d_in[2];
  const float* by0   = (const float*)d_in[3];
  const float* bz0   = (const float*)d_in[4];
  const float* xyz_f = (const float*)d_in[5];
  const float* lb    = (const float*)d_in[6];
  const float* ub    = (const float*)d_in[7];
  const float* W0 = (const float*)d_in[8];
  const float* b0 = (const float*)d_in[9];
  const float* W1 = (const float*)d_in[10];
  const float* b1 = (const float*)d_in[11];
  const float* W2 = (const float*)d_in[12];
  const float* b2 = (const float*)d_in[13];
  const float* W3 = (const float*)d_in[14];
  const float* b3 = (const float*)d_in[15];
  const float* W4 = (const float*)d_in[16];
  const float* b4 = (const float*)d_in[17];
  const float* W5 = (const float*)d_in[18];
  const float* b5 = (const float*)d_in[19];
  const float* W6 = (const float*)d_in[20];
  const float* b6 = (const float*)d_in[21];

  short* Wt = (short*)d_ws;                                   // 655360 B
  float* parts = (float*)((char*)d_ws + 5 * 65536 * sizeof(short));
  float* p_div2 = parts;          // 2048
  float* p_jxb  = parts + 2048;   // 2048
  float* p_bc   = parts + 4096;   // 1024

  prep_kernel<<<1280, 256, 0, stream>>>(W1, W2, W3, W4, W5, Wt);
  field_kernel<<<2048, 256, 0, stream>>>(xyz_f, lb, ub, W0, b0,
      b1, b2, b3, b4, b5, Wt, W6, b6, p_div2, p_jxb);
  bc_kernel<<<1024, 256, 0, stream>>>(x0, y0, bx0, by0, bz0, lb, ub, W0, b0,
      b1, b2, b3, b4, b5, Wt, W6, b6, p_bc);
  reduce_kernel<<<1, 256, 0, stream>>>(parts, (float*)d_out);
}

// Round 5
// 127.465 us; speedup vs baseline: 10.8229x; 1.2676x over previous
//
#include <hip/hip_runtime.h>
#include <math.h>

typedef short bf16x8 __attribute__((ext_vector_type(8)));
typedef short bf16x4 __attribute__((ext_vector_type(4)));
typedef float f32x4 __attribute__((ext_vector_type(4)));

#define NPT0 16384
#define NPTF 32768

__device__ __forceinline__ short f2b(float f) {
  union { float f; unsigned u; } v; v.f = f;
  return (short)((v.u + 0x7FFFu + ((v.u >> 16) & 1u)) >> 16);
}
// packed bf16 pair: lo = bf16(a), hi = bf16(b)
__device__ __forceinline__ int cvtpk(float a, float b) {
  int r;
  asm("v_cvt_pk_bf16_f32 %0, %1, %2" : "=v"(r) : "v"(a), "v"(b));
  return r;
}
// tanh(z) = 1 - 2/(exp(2z)+1). Saturates correctly at +-1 (exp->inf/0).
__device__ __forceinline__ float tanh_fast(float z) {
  const float e = __expf(2.f * z);
  return 1.f - 2.f * __builtin_amdgcn_rcpf(e + 1.f);
}

// act plane layout = exact MFMA B-fragment order, element (p,k) at short idx
//   (k>>5)*512 + (((k>>3)&3)*16 + p)*8 + (k&7)
// so a wave's k-step read is act[ks*512 + lane*8]: 64 lanes x 16B contiguous
// 1KB -> conflict-free ds_read_b128. Plane = 4096 shorts (8KB).

// ---------------------------------------------------------------------------
// prep: W1..W5 fp32 [k][n] -> packed MFMA A-fragment chunks (Wt),
//       W6 fp32 [k][3]     -> zero-padded A-fragment block (at Wt+5*65536).
// Chunk element (l,e) of [layer][nt][ks]: n = nt*16+(l&15), k = ks*32+(l>>4)*8+e
// ---------------------------------------------------------------------------
__global__ void prep_kernel(const float* __restrict__ W1, const float* __restrict__ W2,
                            const float* __restrict__ W3, const float* __restrict__ W4,
                            const float* __restrict__ W5, const float* __restrict__ W6,
                            short* __restrict__ Wt)
{
  const int i = blockIdx.x * 256 + threadIdx.x;   // 0..331775
  if (i < 5 * 65536) {
    const int layer = i >> 16;
    const float* src = layer == 0 ? W1 : layer == 1 ? W2 : layer == 2 ? W3
                     : layer == 3 ? W4 : W5;
    const int w  = i & 65535;
    const int nt = w >> 12;
    const int ks = (w >> 9) & 7;
    const int l  = (w >> 3) & 63;
    const int e  = w & 7;
    const int n  = nt * 16 + (l & 15);
    const int k  = ks * 32 + (l >> 4) * 8 + e;
    Wt[i] = f2b(src[k * 256 + n]);
  } else {
    const int w  = i - 5 * 65536;   // 0..4095
    const int ks = w >> 9;
    const int l  = (w >> 3) & 63;
    const int e  = w & 7;
    const int n  = l & 15;
    const int k  = ks * 32 + (l >> 4) * 8 + e;
    Wt[i] = (n < 3) ? f2b(W6[k * 3 + n]) : (short)0;
  }
}

// ---------------------------------------------------------------------------
// field: 16 pts/block, 4 waves; wave wv owns n-cols [wv*64, wv*64+64).
// MFMA: A = W chunk (rows n), B = act (cols p) -> D[n][p], col=lane&15=p.
// States: 0=h, 1=dx, 2=dy, 3=dz. Tail: per-state MFMA vs padded W6 fragment.
// ---------------------------------------------------------------------------
__global__ __launch_bounds__(256, 3) void field_kernel(
    const float* __restrict__ xyz_f,
    const float* __restrict__ lb, const float* __restrict__ ub,
    const float* __restrict__ W0, const float* __restrict__ b0,
    const float* __restrict__ b1, const float* __restrict__ b2,
    const float* __restrict__ b3, const float* __restrict__ b4,
    const float* __restrict__ b5,
    const short* __restrict__ Wt,
    const float* __restrict__ b6,
    float* __restrict__ part_div2, float* __restrict__ part_jxb)
{
  __shared__ short act[4 * 4096];  // 32 KB: 4 state planes, fragment-linear
  __shared__ float redD[192];      // [state][n(3)][p(16)]
  const int tid = threadIdx.x;
  const int lane = tid & 63;
  const int wv = tid >> 6;       // 0..3
  const int c = lane & 15;
  const int kg = lane >> 4;
  const int nbase = wv * 64;

  const float lbx = lb[0], lby = lb[1], lbz = lb[2];
  const float sx = 2.f / (ub[0] - lbx);
  const float sy = 2.f / (ub[1] - lby);
  const float sz = 2.f / (ub[2] - lbz);

  // ---- layer 0 (3 -> 256): thread t -> point t>>4, 16 neurons ----
  {
    const int p = tid >> 4;
    const int pt = blockIdx.x * 16 + p;
    const int n0 = (tid & 15) * 16;
    const float hx = (xyz_f[pt * 3 + 0] - lbx) * sx - 1.f;
    const float hy = (xyz_f[pt * 3 + 1] - lby) * sy - 1.f;
    const float hz = (xyz_f[pt * 3 + 2] - lbz) * sz - 1.f;
    float th[16], vx[16], vy[16], vz[16];
#pragma unroll
    for (int j = 0; j < 16; ++j) {
      const int n = n0 + j;
      const float w0 = W0[n], w1 = W0[256 + n], w2 = W0[512 + n];
      const float z = b0[n] + hx * w0 + hy * w1 + hz * w2;
      const float t = tanh_fast(z);
      const float g = 1.f - t * t;
      th[j] = t;
      vx[j] = g * sx * w0;
      vy[j] = g * sy * w1;
      vz[j] = g * sz * w2;
    }
    const int ks0 = n0 >> 5;
    const int kgb = (n0 >> 3) & 3;   // 0 or 2
#pragma unroll
    for (int half = 0; half < 2; ++half) {
      const int j0 = half * 8;
      const int idx = ks0 * 512 + ((kgb + half) * 16 + p) * 8;
      int4 o0, o1, o2, o3;
      o0.x = cvtpk(th[j0+0], th[j0+1]); o0.y = cvtpk(th[j0+2], th[j0+3]);
      o0.z = cvtpk(th[j0+4], th[j0+5]); o0.w = cvtpk(th[j0+6], th[j0+7]);
      o1.x = cvtpk(vx[j0+0], vx[j0+1]); o1.y = cvtpk(vx[j0+2], vx[j0+3]);
      o1.z = cvtpk(vx[j0+4], vx[j0+5]); o1.w = cvtpk(vx[j0+6], vx[j0+7]);
      o2.x = cvtpk(vy[j0+0], vy[j0+1]); o2.y = cvtpk(vy[j0+2], vy[j0+3]);
      o2.z = cvtpk(vy[j0+4], vy[j0+5]); o2.w = cvtpk(vy[j0+6], vy[j0+7]);
      o3.x = cvtpk(vz[j0+0], vz[j0+1]); o3.y = cvtpk(vz[j0+2], vz[j0+3]);
      o3.z = cvtpk(vz[j0+4], vz[j0+5]); o3.w = cvtpk(vz[j0+6], vz[j0+7]);
      *(int4*)&act[idx]          = o0;
      *(int4*)&act[4096 + idx]   = o1;
      *(int4*)&act[8192 + idx]   = o2;
      *(int4*)&act[12288 + idx]  = o3;
    }
  }
  __syncthreads();

  const float* const bsArr[5] = {b1, b2, b3, b4, b5};

#pragma unroll
  for (int layer = 0; layer < 5; ++layer) {
    // per-wave packed W chunk pointers: tile t at +t*4096, step ks at +ks*512
    const short* wt0 = Wt + layer * 65536 + wv * 4 * 4096 + lane * 8;
    const short* wt1 = wt0 + 4096;
    const short* wt2 = wt0 + 8192;
    const short* wt3 = wt0 + 12288;

    f32x4 acc[4][4];
#pragma unroll
    for (int s = 0; s < 4; ++s)
#pragma unroll
      for (int t = 0; t < 4; ++t) acc[s][t] = (f32x4){0.f, 0.f, 0.f, 0.f};

#pragma unroll
    for (int ks = 0; ks < 8; ++ks) {
      const int sa = ks * 512 + lane * 8;
      const bf16x8 a0 = *(const bf16x8*)&act[sa];
      const bf16x8 a1 = *(const bf16x8*)&act[4096 + sa];
      const bf16x8 a2 = *(const bf16x8*)&act[8192 + sa];
      const bf16x8 a3 = *(const bf16x8*)&act[12288 + sa];
      const bf16x8 w0 = *(const bf16x8*)(wt0 + ks * 512);
      const bf16x8 w1 = *(const bf16x8*)(wt1 + ks * 512);
      const bf16x8 w2 = *(const bf16x8*)(wt2 + ks * 512);
      const bf16x8 w3 = *(const bf16x8*)(wt3 + ks * 512);
      acc[0][0] = __builtin_amdgcn_mfma_f32_16x16x32_bf16(w0, a0, acc[0][0], 0, 0, 0);
      acc[1][0] = __builtin_amdgcn_mfma_f32_16x16x32_bf16(w0, a1, acc[1][0], 0, 0, 0);
      acc[2][0] = __builtin_amdgcn_mfma_f32_16x16x32_bf16(w0, a2, acc[2][0], 0, 0, 0);
      acc[3][0] = __builtin_amdgcn_mfma_f32_16x16x32_bf16(w0, a3, acc[3][0], 0, 0, 0);
      acc[0][1] = __builtin_amdgcn_mfma_f32_16x16x32_bf16(w1, a0, acc[0][1], 0, 0, 0);
      acc[1][1] = __builtin_amdgcn_mfma_f32_16x16x32_bf16(w1, a1, acc[1][1], 0, 0, 0);
      acc[2][1] = __builtin_amdgcn_mfma_f32_16x16x32_bf16(w1, a2, acc[2][1], 0, 0, 0);
      acc[3][1] = __builtin_amdgcn_mfma_f32_16x16x32_bf16(w1, a3, acc[3][1], 0, 0, 0);
      acc[0][2] = __builtin_amdgcn_mfma_f32_16x16x32_bf16(w2, a0, acc[0][2], 0, 0, 0);
      acc[1][2] = __builtin_amdgcn_mfma_f32_16x16x32_bf16(w2, a1, acc[1][2], 0, 0, 0);
      acc[2][2] = __builtin_amdgcn_mfma_f32_16x16x32_bf16(w2, a2, acc[2][2], 0, 0, 0);
      acc[3][2] = __builtin_amdgcn_mfma_f32_16x16x32_bf16(w2, a3, acc[3][2], 0, 0, 0);
      acc[0][3] = __builtin_amdgcn_mfma_f32_16x16x32_bf16(w3, a0, acc[0][3], 0, 0, 0);
      acc[1][3] = __builtin_amdgcn_mfma_f32_16x16x32_bf16(w3, a1, acc[1][3], 0, 0, 0);
      acc[2][3] = __builtin_amdgcn_mfma_f32_16x16x32_bf16(w3, a2, acc[2][3], 0, 0, 0);
      acc[3][3] = __builtin_amdgcn_mfma_f32_16x16x32_bf16(w3, a3, acc[3][3], 0, 0, 0);
    }
    __syncthreads();  // all LDS reads of layer L done

    // epilogue: lane holds p=c, n = nbase + t*16 + kg*4 + r (r consecutive)
    const float* bl = bsArr[layer];
#pragma unroll
    for (int t = 0; t < 4; ++t) {
      const int n0 = nbase + t * 16 + kg * 4;
      const f32x4 bias = *(const f32x4*)(bl + n0);
      float th[4], g[4];
#pragma unroll
      for (int r = 0; r < 4; ++r) {
        th[r] = tanh_fast(acc[0][t][r] + bias[r]);
        g[r] = 1.f - th[r] * th[r];
      }
      int2 o0, o1, o2, o3;
      o0.x = cvtpk(th[0], th[1]);
      o0.y = cvtpk(th[2], th[3]);
      o1.x = cvtpk(g[0] * acc[1][t][0], g[1] * acc[1][t][1]);
      o1.y = cvtpk(g[2] * acc[1][t][2], g[3] * acc[1][t][3]);
      o2.x = cvtpk(g[0] * acc[2][t][0], g[1] * acc[2][t][1]);
      o2.y = cvtpk(g[2] * acc[2][t][2], g[3] * acc[2][t][3]);
      o3.x = cvtpk(g[0] * acc[3][t][0], g[1] * acc[3][t][1]);
      o3.y = cvtpk(g[2] * acc[3][t][2], g[3] * acc[3][t][3]);
      const int idx = (n0 >> 5) * 512 + (((n0 >> 3) & 3) * 16 + c) * 8 + (n0 & 7);
      *(int2*)&act[idx]         = o0;
      *(int2*)&act[4096 + idx]  = o1;
      *(int2*)&act[8192 + idx]  = o2;
      *(int2*)&act[12288 + idx] = o3;
    }
    __syncthreads();  // layer L+1 act complete
  }

  // ---- layer 6 (256 -> 3) via MFMA: wave wv computes state wv ----
  {
    const short* w6 = Wt + 5 * 65536 + lane * 8;
    f32x4 accT = (f32x4){0.f, 0.f, 0.f, 0.f};
#pragma unroll
    for (int ks = 0; ks < 8; ++ks) {
      const bf16x8 w = *(const bf16x8*)(w6 + ks * 512);
      const bf16x8 b = *(const bf16x8*)&act[wv * 4096 + ks * 512 + lane * 8];
      accT = __builtin_amdgcn_mfma_f32_16x16x32_bf16(w, b, accT, 0, 0, 0);
    }
    if (kg == 0) {
      redD[wv * 48 + 0  + c] = accT[0];
      redD[wv * 48 + 16 + c] = accT[1];
      redD[wv * 48 + 32 + c] = accT[2];
    }
  }
  __syncthreads();
  if (tid < 16) {
    const int p = tid;
    const float bx = redD[0 + p]  + b6[0];
    const float by = redD[16 + p] + b6[1];
    const float bz = redD[32 + p] + b6[2];
    const float j00 = redD[48 + p],  j01 = redD[64 + p],  j02 = redD[80 + p];
    const float j10 = redD[96 + p],  j11 = redD[112 + p], j12 = redD[128 + p];
    const float j20 = redD[144 + p], j21 = redD[160 + p], j22 = redD[176 + p];
    const float dv = j00 + j11 + j22;
    const float jx = j12 - j21;
    const float jy = j20 - j02;
    const float jz = j01 - j10;
    const float e1 = jy * bz - jz * by;
    const float e2 = jz * bx - jx * bz;
    const float e3 = jx * by - jy * bx;
    float d2 = dv * dv;
    float jb = e1 * e1 + e2 * e2 + e3 * e3;
#pragma unroll
    for (int m = 1; m < 16; m <<= 1) {
      d2 += __shfl_xor(d2, m);
      jb += __shfl_xor(jb, m);
    }
    if (tid == 0) {
      part_div2[blockIdx.x] = d2;
      part_jxb[blockIdx.x]  = jb;
    }
  }
}

// ---------------------------------------------------------------------------
// bc: 16 pts/block, 4 waves, 1 state (z=0 plane). Act tile hoisted to regs
// so the W-load+MFMA+epilogue phase runs barrier-free.
// ---------------------------------------------------------------------------
__global__ __launch_bounds__(256, 4) void bc_kernel(
    const float* __restrict__ x0, const float* __restrict__ y0,
    const float* __restrict__ bx0, const float* __restrict__ by0,
    const float* __restrict__ bz0,
    const float* __restrict__ lb, const float* __restrict__ ub,
    const float* __restrict__ W0, const float* __restrict__ b0,
    const float* __restrict__ b1, const float* __restrict__ b2,
    const float* __restrict__ b3, const float* __restrict__ b4,
    const float* __restrict__ b5,
    const short* __restrict__ Wt,
    const float* __restrict__ b6,
    float* __restrict__ part_bc)
{
  __shared__ short act[4096];  // 8 KB, fragment-linear
  const int tid = threadIdx.x;
  const int lane = tid & 63;
  const int wv = tid >> 6;
  const int c = lane & 15;
  const int kg = lane >> 4;
  const int nbase = wv * 64;

  const float lbx = lb[0], lby = lb[1], lbz = lb[2];
  const float sx = 2.f / (ub[0] - lbx);
  const float sy = 2.f / (ub[1] - lby);
  const float sz = 2.f / (ub[2] - lbz);

  // ---- layer 0 ----
  {
    const int p = tid >> 4;
    const int pt = blockIdx.x * 16 + p;
    const int n0 = (tid & 15) * 16;
    const float hx = (x0[pt] - lbx) * sx - 1.f;
    const float hy = (y0[pt] - lby) * sy - 1.f;
    const float hz = (0.f - lbz) * sz - 1.f;
    float th[16];
#pragma unroll
    for (int j = 0; j < 16; ++j) {
      const int n = n0 + j;
      const float z = b0[n] + hx * W0[n] + hy * W0[256 + n] + hz * W0[512 + n];
      th[j] = tanh_fast(z);
    }
    const int ks0 = n0 >> 5;
    const int kgb = (n0 >> 3) & 3;
#pragma unroll
    for (int half = 0; half < 2; ++half) {
      const int j0 = half * 8;
      int4 o;
      o.x = cvtpk(th[j0+0], th[j0+1]); o.y = cvtpk(th[j0+2], th[j0+3]);
      o.z = cvtpk(th[j0+4], th[j0+5]); o.w = cvtpk(th[j0+6], th[j0+7]);
      *(int4*)&act[ks0 * 512 + ((kgb + half) * 16 + p) * 8] = o;
    }
  }
  __syncthreads();

  const float* const bsArr[5] = {b1, b2, b3, b4, b5};

#pragma unroll
  for (int layer = 0; layer < 5; ++layer) {
    const short* wt0 = Wt + layer * 65536 + wv * 4 * 4096 + lane * 8;

    // hoist act reads (32 VGPRs)
    bf16x8 a[8];
#pragma unroll
    for (int ks = 0; ks < 8; ++ks) a[ks] = *(const bf16x8*)&act[ks * 512 + lane * 8];
    __syncthreads();  // reads done -> writes below are safe

    f32x4 acc[4];
#pragma unroll
    for (int t = 0; t < 4; ++t) acc[t] = (f32x4){0.f, 0.f, 0.f, 0.f};

#pragma unroll
    for (int ks = 0; ks < 8; ++ks) {
#pragma unroll
      for (int t = 0; t < 4; ++t) {
        const bf16x8 w = *(const bf16x8*)(wt0 + t * 4096 + ks * 512);
        acc[t] = __builtin_amdgcn_mfma_f32_16x16x32_bf16(w, a[ks], acc[t], 0, 0, 0);
      }
    }

    const float* bl = bsArr[layer];
#pragma unroll
    for (int t = 0; t < 4; ++t) {
      const int n0 = nbase + t * 16 + kg * 4;
      const f32x4 bias = *(const f32x4*)(bl + n0);
      float th[4];
#pragma unroll
      for (int r = 0; r < 4; ++r) th[r] = tanh_fast(acc[t][r] + bias[r]);
      int2 o;
      o.x = cvtpk(th[0], th[1]);
      o.y = cvtpk(th[2], th[3]);
      const int idx = (n0 >> 5) * 512 + (((n0 >> 3) & 3) * 16 + c) * 8 + (n0 & 7);
      *(int2*)&act[idx] = o;
    }
    __syncthreads();  // act[L+1] complete
  }

  // ---- layer 6 + BC loss via MFMA (wave 0 only) ----
  if (wv == 0) {
    const short* w6 = Wt + 5 * 65536 + lane * 8;
    f32x4 accT = (f32x4){0.f, 0.f, 0.f, 0.f};
#pragma unroll
    for (int ks = 0; ks < 8; ++ks) {
      const bf16x8 w = *(const bf16x8*)(w6 + ks * 512);
      const bf16x8 b = *(const bf16x8*)&act[ks * 512 + lane * 8];
      accT = __builtin_amdgcn_mfma_f32_16x16x32_bf16(w, b, accT, 0, 0, 0);
    }
    if (lane < 16) {
      const int pt = blockIdx.x * 16 + lane;
      const float ex = accT[0] + b6[0] - bx0[pt];
      const float ey = accT[1] + b6[1] - by0[pt];
      const float ez = accT[2] + b6[2] - bz0[pt];
      float abc = ex * ex + ey * ey + ez * ez;
#pragma unroll
      for (int m = 1; m < 16; m <<= 1) abc += __shfl_xor(abc, m);
      if (lane == 0) part_bc[blockIdx.x] = abc;
    }
  }
}

// ---------------------------------------------------------------------------
// reduce: parts[0,2048)=div2, [2048,4096)=jxb, [4096,5120)=bc
// ---------------------------------------------------------------------------
__global__ void reduce_kernel(const float* __restrict__ parts, float* __restrict__ out)
{
  __shared__ float sdata[12];
  const int tid = threadIdx.x, lane = tid & 63, wv = tid >> 6;
  float d = 0.f, j = 0.f, b = 0.f;
  for (int i = tid; i < 2048; i += 256) { d += parts[i]; j += parts[2048 + i]; }
  for (int i = tid; i < 1024; i += 256) b += parts[4096 + i];
  for (int off = 32; off > 0; off >>= 1) {
    d += __shfl_down(d, off);
    j += __shfl_down(j, off);
    b += __shfl_down(b, off);
  }
  if (lane == 0) {
    sdata[wv * 3 + 0] = d;
    sdata[wv * 3 + 1] = j;
    sdata[wv * 3 + 2] = b;
  }
  __syncthreads();
  if (tid == 0) {
    float sd = 0.f, sj = 0.f, sb = 0.f;
    for (int w = 0; w < 4; ++w) {
      sd += sdata[w * 3 + 0];
      sj += sdata[w * 3 + 1];
      sb += sdata[w * 3 + 2];
    }
    out[0] = sb / (float)NPT0 + sd / (float)NPTF + sj / (float)NPTF;
  }
}

extern "C" void kernel_launch(void* const* d_in, const int* in_sizes, int n_in,
                              void* d_out, int out_size, void* d_ws, size_t ws_size,
                              hipStream_t stream)
{
  const float* x0    = (const float*)d_in[0];
  const float* y0    = (const float*)d_in[1];
  const float* bx0   = (const float*)d_in[2];
  const float* by0   = (const float*)d_in[3];
  const float* bz0   = (const float*)d_in[4];
  const float* xyz_f = (const float*)d_in[5];
  const float* lb    = (const float*)d_in[6];
  const float* ub    = (const float*)d_in[7];
  const float* W0 = (const float*)d_in[8];
  const float* b0 = (const float*)d_in[9];
  const float* W1 = (const float*)d_in[10];
  const float* b1 = (const float*)d_in[11];
  const float* W2 = (const float*)d_in[12];
  const float* b2 = (const float*)d_in[13];
  const float* W3 = (const float*)d_in[14];
  const float* b3 = (const float*)d_in[15];
  const float* W4 = (const float*)d_in[16];
  const float* b4 = (const float*)d_in[17];
  const float* W5 = (const float*)d_in[18];
  const float* b5 = (const float*)d_in[19];
  const float* W6 = (const float*)d_in[20];
  const float* b6 = (const float*)d_in[21];

  short* Wt = (short*)d_ws;                          // (5*65536 + 4096) shorts
  float* parts = (float*)((char*)d_ws + (5 * 65536 + 4096) * sizeof(short));
  float* p_div2 = parts;          // 2048
  float* p_jxb  = parts + 2048;   // 2048
  float* p_bc   = parts + 4096;   // 1024

  prep_kernel<<<1296, 256, 0, stream>>>(W1, W2, W3, W4, W5, W6, Wt);
  field_kernel<<<2048, 256, 0, stream>>>(xyz_f, lb, ub, W0, b0,
      b1, b2, b3, b4, b5, Wt, b6, p_div2, p_jxb);
  bc_kernel<<<1024, 256, 0, stream>>>(x0, y0, bx0, by0, bz0, lb, ub, W0, b0,
      b1, b2, b3, b4, b5, Wt, b6, p_bc);
  reduce_kernel<<<1, 256, 0, stream>>>(parts, (float*)d_out);
}

// Round 6
// 106.901 us; speedup vs baseline: 12.9048x; 1.1924x over previous
//
#include <hip/hip_runtime.h>
#include <math.h>

typedef short bf16x8 __attribute__((ext_vector_type(8)));
typedef float f32x4 __attribute__((ext_vector_type(4)));

#define NPT0 16384
#define NPTF 32768

__device__ __forceinline__ short f2b(float f) {
  union { float f; unsigned u; } v; v.f = f;
  return (short)((v.u + 0x7FFFu + ((v.u >> 16) & 1u)) >> 16);
}
// packed bf16 pair: lo = bf16(a), hi = bf16(b)
__device__ __forceinline__ int cvtpk(float a, float b) {
  int r;
  asm("v_cvt_pk_bf16_f32 %0, %1, %2" : "=v"(r) : "v"(a), "v"(b));
  return r;
}
// tanh(z) = 1 - 2/(exp(2z)+1). Saturates correctly at +-1 (exp->inf/0).
__device__ __forceinline__ float tanh_fast(float z) {
  const float e = __expf(2.f * z);
  return 1.f - 2.f * __builtin_amdgcn_rcpf(e + 1.f);
}
// short-index of element (n, point-col c) inside one 16-pt fragment-linear
// plane region of 4096 shorts: (n>>5)*512 + (((n>>3)&3)*16 + c)*8 + (n&7)
__device__ __forceinline__ int inplane(int n, int c) {
  return ((n >> 5) << 9) + ((((n >> 3) & 3) * 16 + c) << 3) + (n & 7);
}

// ---------------------------------------------------------------------------
// prep: W1..W5 fp32 [k][n] -> packed MFMA A-fragment chunks (Wt),
//       W6 fp32 [k][3]     -> zero-padded A-fragment block (at Wt+5*65536).
// Chunk element (l,e) of [layer][nt][ks]: n = nt*16+(l&15), k = ks*32+(l>>4)*8+e
// ---------------------------------------------------------------------------
__global__ void prep_kernel(const float* __restrict__ W1, const float* __restrict__ W2,
                            const float* __restrict__ W3, const float* __restrict__ W4,
                            const float* __restrict__ W5, const float* __restrict__ W6,
                            short* __restrict__ Wt)
{
  const int i = blockIdx.x * 256 + threadIdx.x;   // 0..331775
  if (i < 5 * 65536) {
    const int layer = i >> 16;
    const float* src = layer == 0 ? W1 : layer == 1 ? W2 : layer == 2 ? W3
                     : layer == 3 ? W4 : W5;
    const int w  = i & 65535;
    const int nt = w >> 12;
    const int ks = (w >> 9) & 7;
    const int l  = (w >> 3) & 63;
    const int e  = w & 7;
    const int n  = nt * 16 + (l & 15);
    const int k  = ks * 32 + (l >> 4) * 8 + e;
    Wt[i] = f2b(src[k * 256 + n]);
  } else {
    const int w  = i - 5 * 65536;   // 0..4095
    const int ks = w >> 9;
    const int l  = (w >> 3) & 63;
    const int e  = w & 7;
    const int n  = l & 15;
    const int k  = ks * 32 + (l >> 4) * 8 + e;
    Wt[i] = (n < 3) ? f2b(W6[k * 3 + n]) : (short)0;
  }
}

// ---------------------------------------------------------------------------
// field: 32 pts/block, 8 waves; wave wv owns n-tiles {wv*2, wv*2+1}.
// act: state s plane at s*8192 shorts, point-group g at +g*4096 (64 KB).
// MFMA: A = W chunk (16 n), B = act (16 pts) -> D[n][p]; 16 MFMA : 2 W loads.
// ---------------------------------------------------------------------------
__global__ __launch_bounds__(512, 4) void field_kernel(
    const float* __restrict__ xyz_f,
    const float* __restrict__ lb, const float* __restrict__ ub,
    const float* __restrict__ W0, const float* __restrict__ b0,
    const float* __restrict__ b1, const float* __restrict__ b2,
    const float* __restrict__ b3, const float* __restrict__ b4,
    const float* __restrict__ b5,
    const short* __restrict__ Wt,
    const float* __restrict__ b6,
    float* __restrict__ part_div2, float* __restrict__ part_jxb)
{
  __shared__ short act[4 * 8192];  // 64 KB
  __shared__ float redD[4 * 96];   // [s][o][p]: s*96 + o*32 + p
  const int tid = threadIdx.x;
  const int lane = tid & 63;
  const int wv = tid >> 6;         // 0..7
  const int c = lane & 15;
  const int kg = lane >> 4;

  const float lbx = lb[0], lby = lb[1], lbz = lb[2];
  const float sx = 2.f / (ub[0] - lbx);
  const float sy = 2.f / (ub[1] - lby);
  const float sz = 2.f / (ub[2] - lbz);

  // ---- layer 0 (3 -> 256): thread -> point (tid&31), 16 neurons ----
  {
    const int pp = tid & 15;
    const int pg = (tid >> 4) & 1;
    const int pt = blockIdx.x * 32 + pg * 16 + pp;
    const int n0 = (tid >> 5) * 16;
    const float hx = (xyz_f[pt * 3 + 0] - lbx) * sx - 1.f;
    const float hy = (xyz_f[pt * 3 + 1] - lby) * sy - 1.f;
    const float hz = (xyz_f[pt * 3 + 2] - lbz) * sz - 1.f;
    float th[16], vx[16], vy[16], vz[16];
#pragma unroll
    for (int j = 0; j < 16; ++j) {
      const int n = n0 + j;
      const float w0 = W0[n], w1 = W0[256 + n], w2 = W0[512 + n];
      const float z = b0[n] + hx * w0 + hy * w1 + hz * w2;
      const float t = tanh_fast(z);
      const float g = 1.f - t * t;
      th[j] = t;
      vx[j] = g * sx * w0;
      vy[j] = g * sy * w1;
      vz[j] = g * sz * w2;
    }
    const int ks0 = n0 >> 5;
    const int kgb = (n0 >> 3) & 3;   // 0 or 2
#pragma unroll
    for (int half = 0; half < 2; ++half) {
      const int j0 = half * 8;
      const int idx = pg * 4096 + ks0 * 512 + ((kgb + half) * 16 + pp) * 8;
      int4 o0, o1, o2, o3;
      o0.x = cvtpk(th[j0+0], th[j0+1]); o0.y = cvtpk(th[j0+2], th[j0+3]);
      o0.z = cvtpk(th[j0+4], th[j0+5]); o0.w = cvtpk(th[j0+6], th[j0+7]);
      o1.x = cvtpk(vx[j0+0], vx[j0+1]); o1.y = cvtpk(vx[j0+2], vx[j0+3]);
      o1.z = cvtpk(vx[j0+4], vx[j0+5]); o1.w = cvtpk(vx[j0+6], vx[j0+7]);
      o2.x = cvtpk(vy[j0+0], vy[j0+1]); o2.y = cvtpk(vy[j0+2], vy[j0+3]);
      o2.z = cvtpk(vy[j0+4], vy[j0+5]); o2.w = cvtpk(vy[j0+6], vy[j0+7]);
      o3.x = cvtpk(vz[j0+0], vz[j0+1]); o3.y = cvtpk(vz[j0+2], vz[j0+3]);
      o3.z = cvtpk(vz[j0+4], vz[j0+5]); o3.w = cvtpk(vz[j0+6], vz[j0+7]);
      *(int4*)&act[idx]          = o0;
      *(int4*)&act[8192 + idx]   = o1;
      *(int4*)&act[16384 + idx]  = o2;
      *(int4*)&act[24576 + idx]  = o3;
    }
  }
  __syncthreads();

  const float* const bsArr[5] = {b1, b2, b3, b4, b5};

#pragma unroll
  for (int layer = 0; layer < 5; ++layer) {
    const short* wbase = Wt + layer * 65536 + (wv * 2) * 4096 + lane * 8;

    f32x4 acc[2][4][2];  // [t][s][g]
#pragma unroll
    for (int t = 0; t < 2; ++t)
#pragma unroll
      for (int s = 0; s < 4; ++s)
#pragma unroll
        for (int g = 0; g < 2; ++g) acc[t][s][g] = (f32x4){0.f, 0.f, 0.f, 0.f};

#pragma unroll
    for (int ks = 0; ks < 8; ++ks) {
      const int sa = ks * 512 + lane * 8;
      const bf16x8 w0 = *(const bf16x8*)(wbase + ks * 512);
      const bf16x8 w1 = *(const bf16x8*)(wbase + 4096 + ks * 512);
#pragma unroll
      for (int g = 0; g < 2; ++g) {
        const bf16x8 a0 = *(const bf16x8*)&act[g * 4096 + sa];
        const bf16x8 a1 = *(const bf16x8*)&act[8192 + g * 4096 + sa];
        const bf16x8 a2 = *(const bf16x8*)&act[16384 + g * 4096 + sa];
        const bf16x8 a3 = *(const bf16x8*)&act[24576 + g * 4096 + sa];
        acc[0][0][g] = __builtin_amdgcn_mfma_f32_16x16x32_bf16(w0, a0, acc[0][0][g], 0, 0, 0);
        acc[0][1][g] = __builtin_amdgcn_mfma_f32_16x16x32_bf16(w0, a1, acc[0][1][g], 0, 0, 0);
        acc[0][2][g] = __builtin_amdgcn_mfma_f32_16x16x32_bf16(w0, a2, acc[0][2][g], 0, 0, 0);
        acc[0][3][g] = __builtin_amdgcn_mfma_f32_16x16x32_bf16(w0, a3, acc[0][3][g], 0, 0, 0);
        acc[1][0][g] = __builtin_amdgcn_mfma_f32_16x16x32_bf16(w1, a0, acc[1][0][g], 0, 0, 0);
        acc[1][1][g] = __builtin_amdgcn_mfma_f32_16x16x32_bf16(w1, a1, acc[1][1][g], 0, 0, 0);
        acc[1][2][g] = __builtin_amdgcn_mfma_f32_16x16x32_bf16(w1, a2, acc[1][2][g], 0, 0, 0);
        acc[1][3][g] = __builtin_amdgcn_mfma_f32_16x16x32_bf16(w1, a3, acc[1][3][g], 0, 0, 0);
      }
    }
    __syncthreads();  // all LDS reads of layer L done

    // epilogue: lane holds point col c (of group g), n = (wv*2+t)*16 + kg*4 + r
    const float* bl = bsArr[layer];
#pragma unroll
    for (int t = 0; t < 2; ++t) {
      const int n0 = (wv * 2 + t) * 16 + kg * 4;
      const f32x4 bias = *(const f32x4*)(bl + n0);
#pragma unroll
      for (int g = 0; g < 2; ++g) {
        float th[4], gd[4];
#pragma unroll
        for (int r = 0; r < 4; ++r) {
          th[r] = tanh_fast(acc[t][0][g][r] + bias[r]);
          gd[r] = 1.f - th[r] * th[r];
        }
        int2 o0, o1, o2, o3;
        o0.x = cvtpk(th[0], th[1]);
        o0.y = cvtpk(th[2], th[3]);
        o1.x = cvtpk(gd[0] * acc[t][1][g][0], gd[1] * acc[t][1][g][1]);
        o1.y = cvtpk(gd[2] * acc[t][1][g][2], gd[3] * acc[t][1][g][3]);
        o2.x = cvtpk(gd[0] * acc[t][2][g][0], gd[1] * acc[t][2][g][1]);
        o2.y = cvtpk(gd[2] * acc[t][2][g][2], gd[3] * acc[t][2][g][3]);
        o3.x = cvtpk(gd[0] * acc[t][3][g][0], gd[1] * acc[t][3][g][1]);
        o3.y = cvtpk(gd[2] * acc[t][3][g][2], gd[3] * acc[t][3][g][3]);
        const int idx = g * 4096 + inplane(n0, c);
        *(int2*)&act[idx]          = o0;
        *(int2*)&act[8192 + idx]   = o1;
        *(int2*)&act[16384 + idx]  = o2;
        *(int2*)&act[24576 + idx]  = o3;
      }
    }
    __syncthreads();  // layer L+1 act complete
  }

  // ---- layer 6 (256 -> 3) via MFMA: wave wv -> state wv>>1, group wv&1 ----
  {
    const int s = wv >> 1, g = wv & 1;
    const short* w6 = Wt + 5 * 65536 + lane * 8;
    f32x4 accT = (f32x4){0.f, 0.f, 0.f, 0.f};
#pragma unroll
    for (int ks = 0; ks < 8; ++ks) {
      const bf16x8 w = *(const bf16x8*)(w6 + ks * 512);
      const bf16x8 b = *(const bf16x8*)&act[s * 8192 + g * 4096 + ks * 512 + lane * 8];
      accT = __builtin_amdgcn_mfma_f32_16x16x32_bf16(w, b, accT, 0, 0, 0);
    }
    if (kg == 0) {
      redD[s * 96 + 0  + g * 16 + c] = accT[0];
      redD[s * 96 + 32 + g * 16 + c] = accT[1];
      redD[s * 96 + 64 + g * 16 + c] = accT[2];
    }
  }
  __syncthreads();
  if (tid < 32) {
    const int p = tid;
    const float bx = redD[0 + p]   + b6[0];
    const float by = redD[32 + p]  + b6[1];
    const float bz = redD[64 + p]  + b6[2];
    const float j00 = redD[96 + p],  j01 = redD[128 + p], j02 = redD[160 + p];
    const float j10 = redD[192 + p], j11 = redD[224 + p], j12 = redD[256 + p];
    const float j20 = redD[288 + p], j21 = redD[320 + p], j22 = redD[352 + p];
    const float dv = j00 + j11 + j22;
    const float jx = j12 - j21;
    const float jy = j20 - j02;
    const float jz = j01 - j10;
    const float e1 = jy * bz - jz * by;
    const float e2 = jz * bx - jx * bz;
    const float e3 = jx * by - jy * bx;
    float d2 = dv * dv;
    float jb = e1 * e1 + e2 * e2 + e3 * e3;
#pragma unroll
    for (int m = 1; m < 32; m <<= 1) {
      d2 += __shfl_xor(d2, m);
      jb += __shfl_xor(jb, m);
    }
    if (tid == 0) {
      part_div2[blockIdx.x] = d2;
      part_jxb[blockIdx.x]  = jb;
    }
  }
}

// ---------------------------------------------------------------------------
// bc: 32 pts/block, 8 waves, 1 state (z=0 plane). Act hoisted to regs so the
// W-load+MFMA+epilogue phase runs barrier-free.
// ---------------------------------------------------------------------------
__global__ __launch_bounds__(512, 4) void bc_kernel(
    const float* __restrict__ x0, const float* __restrict__ y0,
    const float* __restrict__ bx0, const float* __restrict__ by0,
    const float* __restrict__ bz0,
    const float* __restrict__ lb, const float* __restrict__ ub,
    const float* __restrict__ W0, const float* __restrict__ b0,
    const float* __restrict__ b1, const float* __restrict__ b2,
    const float* __restrict__ b3, const float* __restrict__ b4,
    const float* __restrict__ b5,
    const short* __restrict__ Wt,
    const float* __restrict__ b6,
    float* __restrict__ part_bc)
{
  __shared__ short act[8192];  // 16 KB: group g at g*4096
  __shared__ float red[2];
  const int tid = threadIdx.x;
  const int lane = tid & 63;
  const int wv = tid >> 6;
  const int c = lane & 15;
  const int kg = lane >> 4;

  const float lbx = lb[0], lby = lb[1], lbz = lb[2];
  const float sx = 2.f / (ub[0] - lbx);
  const float sy = 2.f / (ub[1] - lby);
  const float sz = 2.f / (ub[2] - lbz);

  // ---- layer 0 ----
  {
    const int pp = tid & 15;
    const int pg = (tid >> 4) & 1;
    const int pt = blockIdx.x * 32 + pg * 16 + pp;
    const int n0 = (tid >> 5) * 16;
    const float hx = (x0[pt] - lbx) * sx - 1.f;
    const float hy = (y0[pt] - lby) * sy - 1.f;
    const float hz = (0.f - lbz) * sz - 1.f;
    float th[16];
#pragma unroll
    for (int j = 0; j < 16; ++j) {
      const int n = n0 + j;
      const float z = b0[n] + hx * W0[n] + hy * W0[256 + n] + hz * W0[512 + n];
      th[j] = tanh_fast(z);
    }
    const int ks0 = n0 >> 5;
    const int kgb = (n0 >> 3) & 3;
#pragma unroll
    for (int half = 0; half < 2; ++half) {
      const int j0 = half * 8;
      int4 o;
      o.x = cvtpk(th[j0+0], th[j0+1]); o.y = cvtpk(th[j0+2], th[j0+3]);
      o.z = cvtpk(th[j0+4], th[j0+5]); o.w = cvtpk(th[j0+6], th[j0+7]);
      *(int4*)&act[pg * 4096 + ks0 * 512 + ((kgb + half) * 16 + pp) * 8] = o;
    }
  }
  __syncthreads();

  const float* const bsArr[5] = {b1, b2, b3, b4, b5};

#pragma unroll
  for (int layer = 0; layer < 5; ++layer) {
    const short* wbase = Wt + layer * 65536 + (wv * 2) * 4096 + lane * 8;

    // hoist act reads (64 VGPRs)
    bf16x8 a[2][8];
#pragma unroll
    for (int g = 0; g < 2; ++g)
#pragma unroll
      for (int ks = 0; ks < 8; ++ks)
        a[g][ks] = *(const bf16x8*)&act[g * 4096 + ks * 512 + lane * 8];
    __syncthreads();  // reads done -> writes below are safe

    f32x4 acc[2][2];  // [t][g]
#pragma unroll
    for (int t = 0; t < 2; ++t)
#pragma unroll
      for (int g = 0; g < 2; ++g) acc[t][g] = (f32x4){0.f, 0.f, 0.f, 0.f};

#pragma unroll
    for (int ks = 0; ks < 8; ++ks) {
      const bf16x8 w0 = *(const bf16x8*)(wbase + ks * 512);
      const bf16x8 w1 = *(const bf16x8*)(wbase + 4096 + ks * 512);
      acc[0][0] = __builtin_amdgcn_mfma_f32_16x16x32_bf16(w0, a[0][ks], acc[0][0], 0, 0, 0);
      acc[0][1] = __builtin_amdgcn_mfma_f32_16x16x32_bf16(w0, a[1][ks], acc[0][1], 0, 0, 0);
      acc[1][0] = __builtin_amdgcn_mfma_f32_16x16x32_bf16(w1, a[0][ks], acc[1][0], 0, 0, 0);
      acc[1][1] = __builtin_amdgcn_mfma_f32_16x16x32_bf16(w1, a[1][ks], acc[1][1], 0, 0, 0);
    }

    const float* bl = bsArr[layer];
#pragma unroll
    for (int t = 0; t < 2; ++t) {
      const int n0 = (wv * 2 + t) * 16 + kg * 4;
      const f32x4 bias = *(const f32x4*)(bl + n0);
#pragma unroll
      for (int g = 0; g < 2; ++g) {
        float th[4];
#pragma unroll
        for (int r = 0; r < 4; ++r) th[r] = tanh_fast(acc[t][g][r] + bias[r]);
        int2 o;
        o.x = cvtpk(th[0], th[1]);
        o.y = cvtpk(th[2], th[3]);
        *(int2*)&act[g * 4096 + inplane(n0, c)] = o;
      }
    }
    __syncthreads();  // act[L+1] complete
  }

  // ---- layer 6 + BC loss via MFMA (waves 0,1 -> groups 0,1) ----
  if (wv < 2) {
    const int g = wv;
    const short* w6 = Wt + 5 * 65536 + lane * 8;
    f32x4 accT = (f32x4){0.f, 0.f, 0.f, 0.f};
#pragma unroll
    for (int ks = 0; ks < 8; ++ks) {
      const bf16x8 w = *(const bf16x8*)(w6 + ks * 512);
      const bf16x8 b = *(const bf16x8*)&act[g * 4096 + ks * 512 + lane * 8];
      accT = __builtin_amdgcn_mfma_f32_16x16x32_bf16(w, b, accT, 0, 0, 0);
    }
    if (lane < 16) {
      const int pt = blockIdx.x * 32 + g * 16 + lane;
      const float ex = accT[0] + b6[0] - bx0[pt];
      const float ey = accT[1] + b6[1] - by0[pt];
      const float ez = accT[2] + b6[2] - bz0[pt];
      float abc = ex * ex + ey * ey + ez * ez;
#pragma unroll
      for (int m = 1; m < 16; m <<= 1) abc += __shfl_xor(abc, m);
      if (lane == 0) red[g] = abc;
    }
  }
  __syncthreads();
  if (tid == 0) part_bc[blockIdx.x] = red[0] + red[1];
}

// ---------------------------------------------------------------------------
// reduce: parts[0,1024)=div2, [1024,2048)=jxb, [2048,2560)=bc
// ---------------------------------------------------------------------------
__global__ void reduce_kernel(const float* __restrict__ parts, float* __restrict__ out)
{
  __shared__ float sdata[12];
  const int tid = threadIdx.x, lane = tid & 63, wv = tid >> 6;
  float d = 0.f, j = 0.f, b = 0.f;
  for (int i = tid; i < 1024; i += 256) { d += parts[i]; j += parts[1024 + i]; }
  for (int i = tid; i < 512; i += 256) b += parts[2048 + i];
  for (int off = 32; off > 0; off >>= 1) {
    d += __shfl_down(d, off);
    j += __shfl_down(j, off);
    b += __shfl_down(b, off);
  }
  if (lane == 0) {
    sdata[wv * 3 + 0] = d;
    sdata[wv * 3 + 1] = j;
    sdata[wv * 3 + 2] = b;
  }
  __syncthreads();
  if (tid == 0) {
    float sd = 0.f, sj = 0.f, sb = 0.f;
    for (int w = 0; w < 4; ++w) {
      sd += sdata[w * 3 + 0];
      sj += sdata[w * 3 + 1];
      sb += sdata[w * 3 + 2];
    }
    out[0] = sb / (float)NPT0 + sd / (float)NPTF + sj / (float)NPTF;
  }
}

extern "C" void kernel_launch(void* const* d_in, const int* in_sizes, int n_in,
                              void* d_out, int out_size, void* d_ws, size_t ws_size,
                              hipStream_t stream)
{
  const float* x0    = (const float*)d_in[0];
  const float* y0    = (const float*)d_in[1];
  const float* bx0   = (const float*)d_in[2];
  const float* by0   = (const float*)d_in[3];
  const float* bz0   = (const float*)d_in[4];
  const float* xyz_f = (const float*)d_in[5];
  const float* lb    = (const float*)d_in[6];
  const float* ub    = (const float*)d_in[7];
  const float* W0 = (const float*)d_in[8];
  const float* b0 = (const float*)d_in[9];
  const float* W1 = (const float*)d_in[10];
  const float* b1 = (const float*)d_in[11];
  const float* W2 = (const float*)d_in[12];
  const float* b2 = (const float*)d_in[13];
  const float* W3 = (const float*)d_in[14];
  const float* b3 = (const float*)d_in[15];
  const float* W4 = (const float*)d_in[16];
  const float* b4 = (const float*)d_in[17];
  const float* W5 = (const float*)d_in[18];
  const float* b5 = (const float*)d_in[19];
  const float* W6 = (const float*)d_in[20];
  const float* b6 = (const float*)d_in[21];

  short* Wt = (short*)d_ws;                          // (5*65536 + 4096) shorts
  float* parts = (float*)((char*)d_ws + (5 * 65536 + 4096) * sizeof(short));
  float* p_div2 = parts;          // 1024
  float* p_jxb  = parts + 1024;   // 1024
  float* p_bc   = parts + 2048;   // 512

  prep_kernel<<<1296, 256, 0, stream>>>(W1, W2, W3, W4, W5, W6, Wt);
  field_kernel<<<1024, 512, 0, stream>>>(xyz_f, lb, ub, W0, b0,
      b1, b2, b3, b4, b5, Wt, b6, p_div2, p_jxb);
  bc_kernel<<<512, 512, 0, stream>>>(x0, y0, bx0, by0, bz0, lb, ub, W0, b0,
      b1, b2, b3, b4, b5, Wt, b6, p_bc);
  reduce_kernel<<<1, 256, 0, stream>>>(parts, (float*)d_out);
}